// Round 6
// baseline (958.655 us; speedup 1.0000x reference)
//
#include <hip/hip_runtime.h>

#define N_ 6144
#define L_ 1024
#define D_ 512
#define H_ 256
#define SPARSE_MAX 64u

typedef unsigned short u16;
typedef unsigned long long u64;
typedef __attribute__((ext_vector_type(4))) float f32x4;
typedef __attribute__((ext_vector_type(8))) short s16x8;
typedef __attribute__((ext_vector_type(4))) short s16x4;

__device__ __forceinline__ u16 f2b(float f){
  unsigned u = __float_as_uint(f);
  u += 0x7FFFu + ((u >> 16) & 1u);
  return (u16)(u >> 16);
}
__device__ __forceinline__ float b2f(u16 h){ return __uint_as_float(((unsigned)h) << 16); }
__device__ __forceinline__ unsigned fkey(float f){
  unsigned u = __float_as_uint(f);
  return (u & 0x80000000u) ? ~u : (u | 0x80000000u);
}
__device__ __forceinline__ float funkey(unsigned k){
  unsigned u = (k & 0x80000000u) ? (k & 0x7FFFFFFFu) : ~k;
  return __uint_as_float(u);
}
__device__ __forceinline__ float wave_sum(float v){
  #pragma unroll
  for(int o=32;o;o>>=1) v += __shfl_xor(v,o);
  return v;
}
__device__ __forceinline__ float wave_max(float v){
  #pragma unroll
  for(int o=32;o;o>>=1) v = fmaxf(v,__shfl_xor(v,o));
  return v;
}
__device__ __forceinline__ float wave_min(float v){
  #pragma unroll
  for(int o=32;o;o>>=1) v = fminf(v,__shfl_xor(v,o));
  return v;
}
__device__ __forceinline__ float blk_sum256(float v){
  __shared__ float sm[4];
  v = wave_sum(v);
  __syncthreads();
  if((threadIdx.x&63)==0) sm[threadIdx.x>>6]=v;
  __syncthreads();
  return sm[0]+sm[1]+sm[2]+sm[3];
}
__device__ __forceinline__ float blk_min256(float v){
  __shared__ float sm[4];
  v = wave_min(v);
  __syncthreads();
  if((threadIdx.x&63)==0) sm[threadIdx.x>>6]=v;
  __syncthreads();
  return fminf(fminf(sm[0],sm[1]),fminf(sm[2],sm[3]));
}
__device__ __forceinline__ float blk_max256(float v){
  __shared__ float sm[4];
  v = wave_max(v);
  __syncthreads();
  if((threadIdx.x&63)==0) sm[threadIdx.x>>6]=v;
  __syncthreads();
  return fmaxf(fmaxf(sm[0],sm[1]),fmaxf(sm[2],sm[3]));
}

// =================== 256x256 8-phase GEMM (T2+T3+T4+T5) ====================
// C[M,Nc] = A[M,K](bf16,rm) @ Bt[Nc,K](bf16,rm)^T, 512 thr (8 waves, 2Mx4N),
// BK=64, 2 LDS K-tile buffers (128KB), per tile: pre-stage A-halves+vmcnt(4),
// 4 quadrant phases {12 ds_read || stage B-half -> bar -> prio1 -> 16 MFMA ->
// prio0 -> bar}. st_16x32 swizzle both sides. LDS-bounce epilogue.
// MODE 0: bf16 plane z.  MODE 1: NT bf16 + min/max atomics.

#define STG_A(bb,H,Q,KT) __builtin_amdgcn_global_load_lds( \
  (__attribute__((address_space(1))) void*)(gAr + (size_t)((H)*128+(Q)*64)*K + (size_t)(KT)*64), \
  (__attribute__((address_space(3))) void*)(lds + (bb)*16384 + (H)*8192 + (Q)*4096 + (wid<<9)), 16, 0, 0)
#define STG_B(bb,H,Q,KT) __builtin_amdgcn_global_load_lds( \
  (__attribute__((address_space(1))) void*)(gBr + (size_t)((H)*128+(Q)*64)*K + (size_t)(KT)*64), \
  (__attribute__((address_space(3))) void*)(lds + 32768 + (bb)*16384 + (H)*8192 + (Q)*4096 + (wid<<9)), 16, 0, 0)

#define RD(base,row,ks) (*(const s16x8*)(lds + (base) + (row)*64 + ((((ks)<<5) + ((lane>>4)<<3)) ^ (((row)&4)<<2))))

#define MM(i,j,x,y) acc[i][j]=__builtin_amdgcn_mfma_f32_16x16x32_bf16(x,y,acc[i][j],0,0,0)

#define PHASE(QR,QC,EXTRA) do{ \
  s16x8 af0,af1,af2,af3,ag0,ag1,ag2,ag3,bv0,bv1,bw0,bw1; \
  { int r0=(wm<<7)+((QR)<<6)+lr; \
    af0=RD(abase,r0,0);    ag0=RD(abase,r0,1); \
    af1=RD(abase,r0+16,0); ag1=RD(abase,r0+16,1); \
    af2=RD(abase,r0+32,0); ag2=RD(abase,r0+32,1); \
    af3=RD(abase,r0+48,0); ag3=RD(abase,r0+48,1); \
    int s0=(wn<<6)+((QC)<<5)+lr; \
    bv0=RD(bbase,s0,0);    bw0=RD(bbase,s0,1); \
    bv1=RD(bbase,s0+16,0); bw1=RD(bbase,s0+16,1); } \
  EXTRA; \
  __builtin_amdgcn_s_barrier(); \
  __builtin_amdgcn_s_setprio(1); \
  MM((QR)*4+0,(QC)*2+0,af0,bv0); MM((QR)*4+0,(QC)*2+0,ag0,bw0); \
  MM((QR)*4+1,(QC)*2+0,af1,bv0); MM((QR)*4+1,(QC)*2+0,ag1,bw0); \
  MM((QR)*4+2,(QC)*2+0,af2,bv0); MM((QR)*4+2,(QC)*2+0,ag2,bw0); \
  MM((QR)*4+3,(QC)*2+0,af3,bv0); MM((QR)*4+3,(QC)*2+0,ag3,bw0); \
  MM((QR)*4+0,(QC)*2+1,af0,bv1); MM((QR)*4+0,(QC)*2+1,ag0,bw1); \
  MM((QR)*4+1,(QC)*2+1,af1,bv1); MM((QR)*4+1,(QC)*2+1,ag1,bw1); \
  MM((QR)*4+2,(QC)*2+1,af2,bv1); MM((QR)*4+2,(QC)*2+1,ag2,bw1); \
  MM((QR)*4+3,(QC)*2+1,af3,bv1); MM((QR)*4+3,(QC)*2+1,ag3,bw1); \
  __builtin_amdgcn_s_setprio(0); \
  __builtin_amdgcn_s_barrier(); \
}while(0)

template<int MODE>
__global__ __launch_bounds__(512,2) void gemm256(
  const u16* __restrict__ A, const u16* __restrict__ Bt,
  int M, int Nc, int K,
  u16* __restrict__ Cb, unsigned* __restrict__ mmx)
{
  __shared__ __align__(16) u16 lds[65536];   // 128 KB: 2 buf x (A 32K + B 32K)
  const int tid = threadIdx.x;
  const int wid = tid>>6, lane = tid&63;
  const int wm = wid>>2, wn = wid&3;
  const int lr = lane&15;

  const int gx = gridDim.x;
  int lid = blockIdx.y*gx + blockIdx.x;
  const int nwg = gx*gridDim.y;
  if ((nwg & 7) == 0){ const int chunk = nwg>>3; lid = (lid&7)*chunk + (lid>>3); }
  const int m0 = (lid/gx)<<8, n0 = (lid%gx)<<8;

  const int Klen = K/gridDim.z;
  const int kbeg = blockIdx.z*Klen;
  const int NT = Klen>>6;
  const int kt0 = kbeg>>6;

  // staging: per instr (half H, quarter Q): 512thr x 16B = 64 rows of 128B.
  // LDS dest linear; global SOURCE column pre-swizzled (involution with read).
  const int srow = (wid<<3) + (lane>>3);                       // 0..63
  const int scol = ((lane&7)<<3) ^ ((lane&32)>>1);             // elem col, swz
  const u16* gAr = A  + (size_t)(m0 + srow)*K + scol;
  const u16* gBr = Bt + (size_t)(n0 + srow)*K + scol;

  f32x4 acc[8][4] = {};

  // prologue: tile 0 -> buffer 0 (8 loads/wave)
  STG_A(0,0,0,kt0); STG_A(0,0,1,kt0); STG_A(0,1,0,kt0); STG_A(0,1,1,kt0);
  STG_B(0,0,0,kt0); STG_B(0,0,1,kt0); STG_B(0,1,0,kt0); STG_B(0,1,1,kt0);

  for (int t=0; t<NT; ++t){
    const int cbuf = t&1, nbuf = cbuf^1;
    const int abase = cbuf*16384, bbase = 32768 + cbuf*16384;
    const int ktn = kt0 + t + 1;
    if (t+1 < NT){
      STG_A(nbuf,0,0,ktn); STG_A(nbuf,0,1,ktn); STG_A(nbuf,1,0,ktn); STG_A(nbuf,1,1,ktn);
      asm volatile("s_waitcnt vmcnt(4)" ::: "memory");   // tile t fully landed
    } else {
      asm volatile("s_waitcnt vmcnt(0)" ::: "memory");
    }
    __builtin_amdgcn_sched_barrier(0);
    __builtin_amdgcn_s_barrier();
    PHASE(0,0, (void)0 );
    PHASE(0,1, if(t+1<NT){ STG_B(nbuf,0,0,ktn); STG_B(nbuf,0,1,ktn); } );
    PHASE(1,0, if(t+1<NT){ STG_B(nbuf,1,0,ktn); STG_B(nbuf,1,1,ktn); } );
    PHASE(1,1, (void)0 );
  }

  float tmin=3.0e38f, tmax=-3.0e38f;
  if (MODE==1){
    #pragma unroll
    for(int mi=0;mi<8;mi++)
      #pragma unroll
      for(int ni=0;ni<4;ni++){
        f32x4 v=acc[mi][ni];
        #pragma unroll
        for(int e=0;e<4;e++){ tmin=fminf(tmin,v[e]); tmax=fmaxf(tmax,v[e]); }
      }
  }

  // epilogue: 2 passes of 128 rows through LDS -> full-line stores
  __syncthreads();
  #pragma unroll
  for(int p=0;p<2;p++){
    if (wm==p){
      #pragma unroll
      for(int mi=0;mi<8;mi++)
        #pragma unroll
        for(int ni=0;ni<4;ni++){
          f32x4 v=acc[mi][ni];
          int rl=(mi<<4)+((lane>>4)<<2);
          int cl=(wn<<6)+(ni<<4)+lr;
          #pragma unroll
          for(int e=0;e<4;e++) lds[(rl+e)*256+cl]=f2b(v[e]);
        }
    }
    __syncthreads();
    u16* Cp = (MODE==0) ? (Cb + (size_t)blockIdx.z*M*Nc) : Cb;
    #pragma unroll
    for(int it=0;it<8;it++){
      int idx=(it<<12)+(tid<<3);
      int row=idx>>8, col=idx&255;
      s16x8 v=*(const s16x8*)(lds+idx);
      if (MODE==1)
        __builtin_nontemporal_store(v,(s16x8*)(Cp+(size_t)(m0+(p<<7)+row)*Nc+n0+col));
      else
        *(s16x8*)(Cp+(size_t)(m0+(p<<7)+row)*Nc+n0+col)=v;
    }
    __syncthreads();
  }

  if (MODE==1){
    tmin=wave_min(tmin); tmax=wave_max(tmax);
    __shared__ float rmn[8], rmx[8];
    if(lane==0){ rmn[wid]=tmin; rmx[wid]=tmax; }
    __syncthreads();
    if(tid==0){
      float mn=rmn[0], mx=rmx[0];
      #pragma unroll
      for(int i=1;i<8;i++){ mn=fminf(mn,rmn[i]); mx=fmaxf(mx,rmx[i]); }
      atomicMin(mmx+0,fkey(mn));
      atomicMax(mmx+1,fkey(mx));
    }
  }
}

// ---------------- 128x128 GEMM (for skinny / small-K products) -------------
template<int VW> __device__ __forceinline__ void waitv(){
  if constexpr(VW==8) asm volatile("s_waitcnt vmcnt(8)" ::: "memory");
  else if constexpr(VW==4) asm volatile("s_waitcnt vmcnt(4)" ::: "memory");
  else asm volatile("s_waitcnt vmcnt(0)" ::: "memory");
}

#define STG4(bb,k0) do{ \
  __builtin_amdgcn_global_load_lds((__attribute__((address_space(1))) void*)(gA0+(k0)), (__attribute__((address_space(3))) void*)(lds + (bb)*4096 + (wid<<9)),        16, 0, 0); \
  __builtin_amdgcn_global_load_lds((__attribute__((address_space(1))) void*)(gA1+(k0)), (__attribute__((address_space(3))) void*)(lds + (bb)*4096 + 2048 + (wid<<9)), 16, 0, 0); \
  __builtin_amdgcn_global_load_lds((__attribute__((address_space(1))) void*)(gB0+(k0)), (__attribute__((address_space(3))) void*)(lds + 12288 + (bb)*4096 + (wid<<9)),        16, 0, 0); \
  __builtin_amdgcn_global_load_lds((__attribute__((address_space(1))) void*)(gB1+(k0)), (__attribute__((address_space(3))) void*)(lds + 12288 + (bb)*4096 + 2048 + (wid<<9)), 16, 0, 0); \
}while(0)

template<int MODE>
__global__ __launch_bounds__(256) void gemm_bt(
  const u16* __restrict__ A, const u16* __restrict__ Bt,
  int M, int Nc, int K,
  u16* __restrict__ Cb, unsigned* __restrict__ mmx,
  const unsigned* __restrict__ gate)
{
  if (gate && gate[2] <= SPARSE_MAX) return;
  __shared__ __align__(16) u16 lds[3*4096*2];   // 48 KB
  const int tid = threadIdx.x;
  const int wid = tid>>6, lane = tid&63;

  const int gx = gridDim.x;
  int lid = blockIdx.y*gx + blockIdx.x;
  const int nwg = gx*gridDim.y;
  if ((nwg & 7) == 0) {
    const int chunk = nwg >> 3;
    lid = (lid & 7)*chunk + (lid >> 3);
  }
  const int m0 = (lid/gx)<<7, n0 = (lid%gx)<<7;
  const int wr = wid>>1, wc = wid&1;

  const int Klen = K / gridDim.z;
  const int kbeg = blockIdx.z * Klen;

  const int srow = (wid<<4) + (lane>>2);
  const int scol = (lane&3)<<3;
  const u16* gA0 = A  + (size_t)(m0+srow   )*K + scol;
  const u16* gA1 = A  + (size_t)(m0+srow+64)*K + scol;
  const u16* gB0 = Bt + (size_t)(n0+srow   )*K + scol;
  const u16* gB1 = Bt + (size_t)(n0+srow+64)*K + scol;

  f32x4 acc[4][4] = {};
  const int lr = lane&15, lk = (lane>>4)<<3;

  const int NIT = Klen>>5;   // >= 3 required
  STG4(0, kbeg);
  STG4(1, kbeg+32);
  STG4(2, kbeg+64);

  for (int it=0; it<NIT-2; ++it){
    const int b = it - (it/3)*3;
    waitv<8>();
    __builtin_amdgcn_s_barrier();
    const u16* baseA = lds + b*4096;
    const u16* baseB = lds + 12288 + b*4096;
    s16x8 af[4], bfr[4];
    #pragma unroll
    for(int m=0;m<4;m++) af[m]  = *(const s16x8*)(baseA + ((wr<<6)+(m<<4)+lr)*32 + lk);
    #pragma unroll
    for(int n=0;n<4;n++) bfr[n] = *(const s16x8*)(baseB + ((wc<<6)+(n<<4)+lr)*32 + lk);
    asm volatile("s_waitcnt lgkmcnt(0)" ::: "memory");
    __builtin_amdgcn_sched_barrier(0);
    __builtin_amdgcn_s_barrier();
    if (it+3 < NIT) STG4(b, kbeg + ((it+3)<<5));
    #pragma unroll
    for(int m=0;m<4;m++)
      #pragma unroll
      for(int n=0;n<4;n++)
        acc[m][n] = __builtin_amdgcn_mfma_f32_16x16x32_bf16(af[m], bfr[n], acc[m][n], 0,0,0);
  }
  {
    const int it = NIT-2; const int b = it - (it/3)*3;
    waitv<4>();
    __builtin_amdgcn_s_barrier();
    const u16* baseA = lds + b*4096;
    const u16* baseB = lds + 12288 + b*4096;
    s16x8 af[4], bfr[4];
    #pragma unroll
    for(int m=0;m<4;m++) af[m]  = *(const s16x8*)(baseA + ((wr<<6)+(m<<4)+lr)*32 + lk);
    #pragma unroll
    for(int n=0;n<4;n++) bfr[n] = *(const s16x8*)(baseB + ((wc<<6)+(n<<4)+lr)*32 + lk);
    #pragma unroll
    for(int m=0;m<4;m++)
      #pragma unroll
      for(int n=0;n<4;n++)
        acc[m][n] = __builtin_amdgcn_mfma_f32_16x16x32_bf16(af[m], bfr[n], acc[m][n], 0,0,0);
  }
  {
    const int it = NIT-1; const int b = it - (it/3)*3;
    waitv<0>();
    __builtin_amdgcn_s_barrier();
    const u16* baseA = lds + b*4096;
    const u16* baseB = lds + 12288 + b*4096;
    s16x8 af[4], bfr[4];
    #pragma unroll
    for(int m=0;m<4;m++) af[m]  = *(const s16x8*)(baseA + ((wr<<6)+(m<<4)+lr)*32 + lk);
    #pragma unroll
    for(int n=0;n<4;n++) bfr[n] = *(const s16x8*)(baseB + ((wc<<6)+(n<<4)+lr)*32 + lk);
    #pragma unroll
    for(int m=0;m<4;m++)
      #pragma unroll
      for(int n=0;n<4;n++)
        acc[m][n] = __builtin_amdgcn_mfma_f32_16x16x32_bf16(af[m], bfr[n], acc[m][n], 0,0,0);
  }

  __syncthreads();
  u16* lC = lds;
  {
    const int rb_l = (wr<<6) + ((lane>>4)<<2);
    const int cb_l = (wc<<6) + lr;
    #pragma unroll
    for(int m=0;m<4;m++)
      #pragma unroll
      for(int n=0;n<4;n++){
        f32x4 v = acc[m][n];
        #pragma unroll
        for(int e=0;e<4;e++)
          lC[(rb_l+(m<<4)+e)*128 + cb_l+(n<<4)] = f2b(v[e]);
      }
  }
  __syncthreads();
  u16* Cp = Cb + (size_t)blockIdx.z * M * Nc;
  #pragma unroll
  for(int q=0;q<8;q++){
    int c = (q<<8) + tid;
    int r = c>>4, cc = (c&15)<<3;
    *(s16x8*)(Cp + (size_t)(m0+r)*Nc + n0 + cc) = *(const s16x8*)(lC + r*128 + cc);
  }
  (void)mmx;
}

// src [R][C] fp32 -> dst [C][R] bf16   (weight prep)
__global__ __launch_bounds__(256) void transpose_cast(
  const float* __restrict__ src, u16* __restrict__ dst, int R, int C)
{
  __shared__ float t[32][33];
  int c0 = blockIdx.x<<5, r0 = blockIdx.y<<5;
  int tx = threadIdx.x&31, ty = threadIdx.x>>5;
  #pragma unroll
  for(int i=0;i<32;i+=8) t[ty+i][tx] = src[(size_t)(r0+ty+i)*C + c0+tx];
  __syncthreads();
  #pragma unroll
  for(int i=0;i<32;i+=8) dst[(size_t)(c0+ty+i)*R + r0+tx] = f2b(t[tx][ty+i]);
}

// dst[C][R] bf16 = transpose( sum_p bf16_plane_p [R][C] ); gated (dense path)
__global__ __launch_bounds__(256) void transpose_sum_bf(
  const u16* __restrict__ src, size_t pstr, int nsp,
  u16* __restrict__ dst, int R, int C, const unsigned* __restrict__ gate)
{
  if (gate && gate[2] <= SPARSE_MAX) return;
  __shared__ float t[32][33];
  int c0 = blockIdx.x<<5, r0 = blockIdx.y<<5;
  int tx = threadIdx.x&31, ty = threadIdx.x>>5;
  #pragma unroll
  for(int i=0;i<32;i+=8){
    float v = 0;
    for(int p=0;p<nsp;p++)
      v += b2f(src[(size_t)p*pstr + (size_t)(r0+ty+i)*C + c0+tx]);
    t[ty+i][tx] = v;
  }
  __syncthreads();
  #pragma unroll
  for(int i=0;i<32;i+=8) dst[(size_t)(c0+ty+i)*R + r0+tx] = f2b(t[tx][ty+i]);
}

__global__ __launch_bounds__(256) void prep_x(const float* __restrict__ x,
  u16* __restrict__ xb, u16* __restrict__ xnb)
{
  int row = blockIdx.x, t = threadIdx.x;
  const float* p = x + (size_t)row*L_ + (t<<2);
  f32x4 v = *(const f32x4*)p;
  float ss = v[0]*v[0]+v[1]*v[1]+v[2]*v[2]+v[3]*v[3];
  float tot = blk_sum256(ss);
  float inv = 1.0f/fmaxf(sqrtf(tot), 1e-12f);
  u16* pb = xb  + (size_t)row*L_ + (t<<2);
  u16* pn = xnb + (size_t)row*L_ + (t<<2);
  #pragma unroll
  for(int k=0;k<4;k++){ pb[k]=f2b(v[k]); pn[k]=f2b(v[k]*inv); }
}

// fused-projection epilogue: a at cols [0,256), b at [256,512) of [N,1536] planes
__global__ __launch_bounds__(256) void attn_epi(const u16* __restrict__ SPA,
  size_t pstr, int nsp,
  const float* __restrict__ ba, const float* __restrict__ bb,
  const float* __restrict__ wc, const float* __restrict__ bc,
  float* __restrict__ agg, float* __restrict__ s)
{
  int row = (blockIdx.x<<2) + (threadIdx.x>>6);
  int lane = threadIdx.x&63;
  float a[4]={0,0,0,0}, b[4]={0,0,0,0};
  for(int p=0;p<nsp;p++){
    s16x4 ua = *(const s16x4*)(SPA + (size_t)p*pstr + (size_t)row*1536 + (lane<<2));
    s16x4 ub = *(const s16x4*)(SPA + (size_t)p*pstr + (size_t)row*1536 + 256 + (lane<<2));
    #pragma unroll
    for(int j=0;j<4;j++){ a[j]+=b2f((u16)ua[j]); b[j]+=b2f((u16)ub[j]); }
  }
  float acc=0;
  #pragma unroll
  for(int j=0;j<4;j++){
    int h = (lane<<2)+j;
    float tv = tanhf(a[j]+ba[h]);
    float sg = 1.0f/(1.0f+expf(-(b[j]+bb[h])));
    acc += tv*sg*wc[h];
  }
  acc = wave_sum(acc);
  if(lane==0){
    float v = acc + bc[0];
    agg[row]=v;
    s[row]=1.0f/(1.0f+expf(-v));
  }
}

__global__ __launch_bounds__(256) void s_stats(const float* __restrict__ s, float* __restrict__ sc){
  int t=threadIdx.x;
  float sum=0, mn=3e38f, mx=-3e38f;
  for(int i=t;i<N_;i+=256){ float v=s[i]; sum+=v; mn=fminf(mn,v); mx=fmaxf(mx,v); }
  float S=blk_sum256(sum);
  float MN=blk_min256(mn);
  float MX=blk_max256(mx);
  if(t==0){ sc[0]=S; sc[1]=MN; sc[2]=MX; }
}

__global__ __launch_bounds__(256) void aw_write(const float* __restrict__ maps, const float* __restrict__ s,
  const float* __restrict__ sc, u16* __restrict__ awb)
{
  int i = blockIdx.x, t = threadIdx.x;
  float smin = sc[1], smax = sc[2];
  float mn = smin*smin, mx = smax*smax;
  float beta = 0.6f/(mx-mn);
  float c1 = 0.4f - beta*mn;
  float si = s[i];
  const float* mrow = maps + (size_t)i*N_;
  float mv[24];
  float part = 0;
  #pragma unroll
  for(int q=0;q<24;q++){
    int j = t + (q<<8);
    mv[q] = c1 + beta*si*s[j] + mrow[j];
    part += mv[q];
  }
  float r = blk_sum256(part);
  float inv = 1.0f/fmaxf(r, 1e-12f);
  u16* orow = awb + (size_t)i*N_;
  #pragma unroll
  for(int q=0;q<24;q++)
    __builtin_nontemporal_store(f2b(mv[q]*inv), orow + t + (q<<8));
}

// out = relu(LN( (sum_p Y_p)*rowscale + bias )).  If gate says sparse, read
// Yalt ([N,512], 1 plane) instead of Y.
__global__ __launch_bounds__(256) void ln_epi512(const u16* __restrict__ Y, size_t pstr, int nsp,
  int rs, int cbase,
  const float* __restrict__ ki,
  const float* __restrict__ bias, const float* __restrict__ g, const float* __restrict__ bn,
  u16* __restrict__ outb,
  const unsigned* __restrict__ gate, const u16* __restrict__ Yalt)
{
  const u16* src = Y; size_t ps = pstr; int np = nsp, rstride = rs, cb = cbase;
  if (gate && gate[2] <= SPARSE_MAX){ src = Yalt; ps = 0; np = 1; rstride = 512; cb = 0; }
  int row = (blockIdx.x<<2)+(threadIdx.x>>6);
  int lane = threadIdx.x&63;
  int c0 = lane<<3;
  float v[8] = {0,0,0,0,0,0,0,0};
  for(int p=0;p<np;p++){
    s16x8 u = *(const s16x8*)(src + (size_t)p*ps + (size_t)row*rstride + cb + c0);
    #pragma unroll
    for(int j=0;j<8;j++) v[j] += b2f((u16)u[j]);
  }
  float scale = ki ? (1.0f/ki[row]) : 1.0f;
  float sum=0, ssum=0;
  #pragma unroll
  for(int j=0;j<8;j++){ v[j] = v[j]*scale + bias[c0+j]; sum+=v[j]; ssum+=v[j]*v[j]; }
  sum = wave_sum(sum); ssum = wave_sum(ssum);
  float m = sum*(1.0f/D_);
  float var = ssum*(1.0f/D_) - m*m;
  float invsd = rsqrtf(var + 1e-5f);
  u16 ob[8];
  #pragma unroll
  for(int j=0;j<8;j++){
    float o = (v[j]-m)*invsd*g[c0+j] + bn[c0+j];
    o = fmaxf(o, 0.0f);
    ob[j] = f2b(o);
  }
  *(s16x8*)(outb + (size_t)row*D_ + c0) = *(s16x8*)ob;
}

__global__ __launch_bounds__(256) void bias_cast(const u16* __restrict__ Y, size_t pstr, int nsp,
  const float* __restrict__ b, u16* __restrict__ outb)
{
  size_t idx = ((size_t)blockIdx.x*256 + threadIdx.x)<<3;
  float v[8] = {0,0,0,0,0,0,0,0};
  for(int p=0;p<nsp;p++){
    s16x8 u = *(const s16x8*)(Y + (size_t)p*pstr + idx);
    #pragma unroll
    for(int j=0;j<8;j++) v[j] += b2f((u16)u[j]);
  }
  int c = (int)(idx & (D_-1));
  u16 ob[8];
  #pragma unroll
  for(int k=0;k<8;k++) ob[k] = f2b(v[k]+b[c+k]);
  *(s16x8*)(outb+idx) = *(s16x8*)ob;
}

__global__ void init_k(unsigned* mmx){ mmx[0]=0xFFFFFFFFu; mmx[1]=0u; mmx[2]=0u; }

// binarize in place + bitmap + per-row count + max-nnz + fused trans/z
__global__ __launch_bounds__(256) void binarize(u16* __restrict__ csb,
  unsigned* __restrict__ mmx, const float* __restrict__ agg,
  float* __restrict__ ki, float* __restrict__ z, u64* __restrict__ bm)
{
  int i = blockIdx.x, t = threadIdx.x;
  int lane = t&63, w = t>>6;
  float mn = funkey(mmx[0]), mx = funkey(mmx[1]);
  float th = mn + 0.5f*(mx-mn);
  u16* row = csb + (size_t)i*N_;
  u64* bmrow = bm + (size_t)i*96;
  float cnt = 0, dot = 0;
  #pragma unroll
  for(int q=0;q<24;q++){
    int j = t + (q<<8);
    bool on = b2f(row[j]) >= th;
    __builtin_nontemporal_store(on ? (u16)0x3F80 : (u16)0, row + j);
    u64 mask = __ballot(on);
    if(lane==0) bmrow[(q<<2)+w] = mask;
    if(on){ cnt += 1.0f; dot += agg[j]; }
  }
  float k = blk_sum256(cnt);
  float dt = blk_sum256(dot);
  if(t==0){
    ki[i] = k;
    float tr = dt/(k*sqrtf((float)N_));
    z[i] = 0.3f*tr + 0.7f*agg[i];
    atomicMax(mmx+2, (unsigned)(k+0.5f));
  }
}

// sparse adjacency apply: YS[i,:] = sum_{j: bit set} sum_p SP[p][j,:]
__global__ __launch_bounds__(256) void gather_rows(const u64* __restrict__ bm,
  const u16* __restrict__ SPp, size_t pstr, int nsp,
  const unsigned* __restrict__ gate, u16* __restrict__ YS)
{
  if (gate[2] > SPARSE_MAX) return;
  int i = blockIdx.x, t = threadIdx.x;
  __shared__ u64 wbuf[96];
  __shared__ u16 idx[SPARSE_MAX];
  __shared__ int nn_s;
  if (t < 96) wbuf[t] = bm[(size_t)i*96 + t];
  __syncthreads();
  if (t == 0){
    int nn = 0;
    for(int k=0;k<96;k++){
      u64 m = wbuf[k];
      while(m && nn < (int)SPARSE_MAX){
        int b = __ffsll((long long)m) - 1;
        m &= m - 1;
        idx[nn++] = (u16)((k<<6) + b);
      }
    }
    nn_s = nn;
  }
  __syncthreads();
  int nn = nn_s;
  float a0=0, a1=0;
  for(int k=0;k<nn;k++){
    size_t jb = (size_t)idx[k]*512;
    for(int p=0;p<nsp;p++){
      a0 += b2f(SPp[p*pstr + jb + t]);
      a1 += b2f(SPp[p*pstr + jb + t + 256]);
    }
  }
  YS[(size_t)i*512 + t]       = f2b(a0);
  YS[(size_t)i*512 + t + 256] = f2b(a1);
}

__global__ __launch_bounds__(1024) void softmax_prep(const float* __restrict__ z,
  float* __restrict__ e, float* __restrict__ sexp)
{
  int t = threadIdx.x;
  __shared__ float sm[16];
  float mx=-3e38f;
  for(int i=t;i<N_;i+=1024) mx=fmaxf(mx,z[i]);
  mx = wave_max(mx);
  if((t&63)==0) sm[t>>6]=mx;
  __syncthreads();
  float zm = sm[0];
  #pragma unroll
  for(int w=1;w<16;w++) zm=fmaxf(zm,sm[w]);
  __syncthreads();
  float sum=0;
  for(int i=t;i<N_;i+=1024){ float ee=expf(z[i]-zm); e[i]=ee; sum+=ee; }
  sum = wave_sum(sum);
  if((t&63)==0) sm[t>>6]=sum;
  __syncthreads();
  if(t==0){ float S=0; for(int w=0;w<16;w++) S+=sm[w]; *sexp=S; }
}

__global__ __launch_bounds__(256) void pooled_partial(const float* __restrict__ e,
  const u16* __restrict__ g2b, const u16* __restrict__ g1b, float* __restrict__ part)
{
  int b = blockIdx.x, t = threadIdx.x;
  float a0=0,a1=0,a2=0,a3=0;
  for(int r=0;r<24;r++){
    int row = b*24+r;
    float w = e[row];
    a0 += w * b2f(g2b[(size_t)row*D_ + t]);
    a1 += w * b2f(g2b[(size_t)row*D_ + t+256]);
    a2 += w * b2f(g1b[(size_t)row*D_ + t]);
    a3 += w * b2f(g1b[(size_t)row*D_ + t+256]);
  }
  part[(size_t)b*1024 + t]      = a0;
  part[(size_t)b*1024 + t+256]  = a1;
  part[(size_t)b*1024 + t+512]  = a2;
  part[(size_t)b*1024 + t+768]  = a3;
}

__global__ __launch_bounds__(1024) void final_k(const float* __restrict__ part, const float* __restrict__ sexp,
  const float* __restrict__ lng, const float* __restrict__ lnb,
  const float* __restrict__ clsw, float* __restrict__ out)
{
  int t = threadIdx.x;
  __shared__ float red[16];
  __shared__ float smv[1024];
  __shared__ float lgs[4];
  float p=0;
  for(int b=0;b<256;b++) p += part[b*1024 + t];
  p /= sexp[0];
  float w = wave_sum(p);
  if((t&63)==0) red[t>>6]=w;
  __syncthreads();
  float tot=0;
  #pragma unroll
  for(int i2=0;i2<16;i2++) tot+=red[i2];
  float m = tot*(1.0f/1024.0f);
  __syncthreads();
  float d = p-m;
  w = wave_sum(d*d);
  if((t&63)==0) red[t>>6]=w;
  __syncthreads();
  tot=0;
  #pragma unroll
  for(int i2=0;i2<16;i2++) tot+=red[i2];
  float var = tot*(1.0f/1024.0f);
  float y = d*rsqrtf(var+1e-5f)*lng[t] + lnb[t];
  smv[t]=y;
  __syncthreads();
  if(t<4){
    float lg=0;
    for(int j=0;j<1024;j++) lg += smv[j]*clsw[j*4+t];
    lgs[t]=lg;
  }
  __syncthreads();
  if(t==0){
    float h[4];
    int am=0; float best=lgs[0];
    #pragma unroll
    for(int c2=0;c2<4;c2++){ h[c2]=1.0f/(1.0f+expf(-lgs[c2])); if(lgs[c2]>best){best=lgs[c2];am=c2;} }
    float sv=1.0f;
    #pragma unroll
    for(int c2=0;c2<4;c2++){ out[c2]=h[c2]; sv*=(1.0f-h[c2]); out[4+c2]=sv; }
    out[8]=(float)am;
  }
}

extern "C" void kernel_launch(void* const* d_in, const int* in_sizes, int n_in,
                              void* d_out, int out_size, void* d_ws, size_t ws_size,
                              hipStream_t stream)
{
  const float* x_path =(const float*)d_in[0];
  const float* maps   =(const float*)d_in[1];
  const float* nl0_w1 =(const float*)d_in[2];
  const float* nl0_b1 =(const float*)d_in[3];
  const float* nl0_g  =(const float*)d_in[4];
  const float* nl0_bn =(const float*)d_in[5];
  const float* nl0_w2 =(const float*)d_in[6];
  const float* nl0_b2 =(const float*)d_in[7];
  const float* nl1_w1 =(const float*)d_in[8];
  const float* nl1_b1 =(const float*)d_in[9];
  const float* nl1_g  =(const float*)d_in[10];
  const float* nl1_bn =(const float*)d_in[11];
  const float* nl1_w2 =(const float*)d_in[12];
  const float* nl1_b2 =(const float*)d_in[13];
  const float *gw[6], *gb[6], *gg[6], *gbn[6];   // gc0,gc1,gc2,ga0,ga1,ga2
  for(int l=0;l<6;l++){
    gw[l]  = (const float*)d_in[14+l*4+0];
    gb[l]  = (const float*)d_in[14+l*4+1];
    gg[l]  = (const float*)d_in[14+l*4+2];
    gbn[l] = (const float*)d_in[14+l*4+3];
  }
  const float* attn_wa=(const float*)d_in[38];
  const float* attn_ba=(const float*)d_in[39];
  const float* attn_wb=(const float*)d_in[40];
  const float* attn_bb=(const float*)d_in[41];
  const float* attn_wc=(const float*)d_in[42];
  const float* attn_bc=(const float*)d_in[43];
  const float* cls_w  =(const float*)d_in[44];
  const float* ln_g   =(const float*)d_in[45];
  const float* ln_b   =(const float*)d_in[46];

  char* ws=(char*)d_ws;
  size_t off=0;
  auto alc=[&](size_t b)->char*{ char* p=ws+off; off=(off+b+255)&~(size_t)255; return p; };
  u16* BIG = (u16*)alc((size_t)N_*N_*2);          // aw, then cs/binary (time-shared)
  u16* XB  = (u16*)alc((size_t)N_*L_*2);
  u16* XNB = (u16*)alc((size_t)N_*L_*2);
  u16* WT_proj=(u16*)alc((size_t)1536*L_*2);      // [wa;wb;nl0w1;nl1w1] transposed
  u16* WT_nl0w2=(u16*)alc((size_t)D_*D_*2);
  u16* WT_nl1w2=(u16*)alc((size_t)D_*D_*2);
  u16* WT_g[6];
  for(int l=0;l<6;l++) WT_g[l]=(u16*)alc((size_t)D_*D_*2);
  u16* SP = (u16*)alc((size_t)2*N_*1536*2);       // split planes (max: proj SK=2)
  u16* XWT=(u16*)alc((size_t)D_*N_*2);
  u16* XA0=(u16*)alc((size_t)N_*D_*2);
  u16* XA1=(u16*)alc((size_t)N_*D_*2);
  u16* X0B=(u16*)alc((size_t)N_*D_*2);
  u16* X1B=(u16*)alc((size_t)N_*D_*2);
  u16* YS =(u16*)alc((size_t)N_*D_*2);
  u64* BM =(u64*)alc((size_t)N_*96*8);
  float* PART=(float*)alc((size_t)256*1024*4);
  float* AGG=(float*)alc(N_*4);
  float* SS =(float*)alc(N_*4);
  float* KI =(float*)alc(N_*4);
  float* Z  =(float*)alc(N_*4);
  float* E  =(float*)alc(N_*4);
  float* SC =(float*)alc(256);
  unsigned* MMX=(unsigned*)alc(256);
  float* SEXP=(float*)alc(256);

  const size_t PS_D = (size_t)N_*D_;      // 512-col plane stride
  const size_t PS_P = (size_t)N_*1536;    // proj plane stride

  init_k<<<1,1,0,stream>>>(MMX);
  prep_x<<<N_,256,0,stream>>>(x_path, XB, XNB);

  // weight prep
  transpose_cast<<<dim3(H_/32, L_/32),256,0,stream>>>(attn_wa, WT_proj,                   L_, H_);
  transpose_cast<<<dim3(H_/32, L_/32),256,0,stream>>>(attn_wb, WT_proj + (size_t)256*L_,  L_, H_);
  transpose_cast<<<dim3(D_/32, L_/32),256,0,stream>>>(nl0_w1,  WT_proj + (size_t)512*L_,  L_, D_);
  transpose_cast<<<dim3(D_/32, L_/32),256,0,stream>>>(nl1_w1,  WT_proj + (size_t)1024*L_, L_, D_);
  transpose_cast<<<dim3(D_/32, D_/32),256,0,stream>>>(nl0_w2, WT_nl0w2, D_, D_);
  transpose_cast<<<dim3(D_/32, D_/32),256,0,stream>>>(nl1_w2, WT_nl1w2, D_, D_);
  for(int l=0;l<6;l++)
    transpose_cast<<<dim3(D_/32, D_/32),256,0,stream>>>(gw[l], WT_g[l], D_, D_);

  // fused X projections: [a|b|h0|h1] = XB @ WT_proj^T  (SK=2)
  gemm_bt<0><<<dim3(1536/128, N_/128, 2),256,0,stream>>>(XB, WT_proj, N_, 1536, L_, SP, nullptr, nullptr);
  attn_epi<<<N_/4,256,0,stream>>>(SP, PS_P, 2, attn_ba, attn_bb, attn_wc, attn_bc, AGG, SS);
  s_stats<<<1,256,0,stream>>>(SS,SC);
  aw_write<<<N_,256,0,stream>>>(maps,SS,SC,BIG);

  ln_epi512<<<N_/4,256,0,stream>>>(SP,PS_P,2, 1536,1024, nullptr, nl1_b1,nl1_g,nl1_bn, XA1, nullptr,nullptr);
  ln_epi512<<<N_/4,256,0,stream>>>(SP,PS_P,2, 1536, 512, nullptr, nl0_b1,nl0_g,nl0_bn, XA0, nullptr,nullptr);

  gemm_bt<0><<<dim3(D_/128,N_/128,4),256,0,stream>>>(XA1, WT_nl1w2, N_,D_,D_, SP, nullptr, nullptr);
  bias_cast<<<(N_*D_/8)/256,256,0,stream>>>(SP,PS_D,4, nl1_b2, X1B);

  // ga chain (dense adjacency = BIG = aw) -- 256x256 8-phase GEMM
  {
    const u16* cur=X1B;
    for(int l=0;l<3;l++){
      int gi = 3+l;
      gemm_bt<0><<<dim3(D_/128,N_/128,4),256,0,stream>>>(cur, WT_g[gi], N_,D_,D_, SP, nullptr, nullptr);
      transpose_sum_bf<<<dim3(D_/32, N_/32),256,0,stream>>>(SP, PS_D, 4, XWT, N_, D_, nullptr);
      gemm256<0><<<dim3(D_/256, N_/256, 4),512,0,stream>>>(BIG, XWT, N_,D_,N_, SP, nullptr);
      u16* nxt = (l==0)? XA1 : (l==1)? YS : X1B;
      ln_epi512<<<N_/4,256,0,stream>>>(SP,PS_D,4, 512,0, nullptr, gb[gi],gg[gi],gbn[gi], nxt, nullptr,nullptr);
      cur = nxt;
    }
  }

  gemm_bt<0><<<dim3(D_/128,N_/128,4),256,0,stream>>>(XA0, WT_nl0w2, N_,D_,D_, SP, nullptr, nullptr);
  bias_cast<<<(N_*D_/8)/256,256,0,stream>>>(SP,PS_D,4, nl0_b2, X0B);

  // cosine gram -> BIG (NT bf16) + min/max -- 256x256 8-phase GEMM
  gemm256<1><<<dim3(N_/256, N_/256, 1),512,0,stream>>>(XNB, XNB, N_,N_,L_, BIG, MMX);
  binarize<<<N_,256,0,stream>>>(BIG, MMX, AGG, KI, Z, BM);

  // gc chain: sparse gather path (gated) with dense GEMM fallback
  {
    const u16* cur=X0B;
    for(int l=0;l<3;l++){
      int gi = l;
      gemm_bt<0><<<dim3(D_/128,N_/128,4),256,0,stream>>>(cur, WT_g[gi], N_,D_,D_, SP, nullptr, nullptr);
      transpose_sum_bf<<<dim3(D_/32, N_/32),256,0,stream>>>(SP, PS_D, 4, XWT, N_, D_, MMX);
      gemm_bt<0><<<dim3(D_/128,N_/128,4),256,0,stream>>>(BIG, XWT, N_,D_,N_, SP, nullptr, MMX);
      gather_rows<<<N_,256,0,stream>>>(BM, SP, PS_D, 4, MMX, YS);
      u16* nxt = (l==0)? XA1 : (l==1)? XA0 : X0B;
      ln_epi512<<<N_/4,256,0,stream>>>(SP,PS_D,4, 512,0, KI, gb[gi],gg[gi],gbn[gi], nxt, MMX, YS);
      cur = nxt;
    }
  }

  // pooling + head
  softmax_prep<<<1,1024,0,stream>>>(Z,E,SEXP);
  pooled_partial<<<256,256,0,stream>>>(E,X1B,X0B,PART);
  final_k<<<1,1024,0,stream>>>(PART,SEXP,ln_g,ln_b,cls_w,(float*)d_out);

  (void)in_sizes;(void)n_in;(void)out_size;(void)ws_size;
}

// Round 7
// 887.136 us; speedup vs baseline: 1.0806x; 1.0806x over previous
//
#include <hip/hip_runtime.h>

#define N_ 6144
#define L_ 1024
#define D_ 512
#define H_ 256
#define SPARSE_MAX 64u

typedef unsigned short u16;
typedef unsigned long long u64;
typedef __attribute__((ext_vector_type(4))) float f32x4;
typedef __attribute__((ext_vector_type(8))) short s16x8;
typedef __attribute__((ext_vector_type(4))) short s16x4;

__device__ __forceinline__ u16 f2b(float f){
  unsigned u = __float_as_uint(f);
  u += 0x7FFFu + ((u >> 16) & 1u);
  return (u16)(u >> 16);
}
__device__ __forceinline__ float b2f(u16 h){ return __uint_as_float(((unsigned)h) << 16); }
__device__ __forceinline__ unsigned fkey(float f){
  unsigned u = __float_as_uint(f);
  return (u & 0x80000000u) ? ~u : (u | 0x80000000u);
}
__device__ __forceinline__ float funkey(unsigned k){
  unsigned u = (k & 0x80000000u) ? (k & 0x7FFFFFFFu) : ~k;
  return __uint_as_float(u);
}
__device__ __forceinline__ float wave_sum(float v){
  #pragma unroll
  for(int o=32;o;o>>=1) v += __shfl_xor(v,o);
  return v;
}
__device__ __forceinline__ float wave_max(float v){
  #pragma unroll
  for(int o=32;o;o>>=1) v = fmaxf(v,__shfl_xor(v,o));
  return v;
}
__device__ __forceinline__ float wave_min(float v){
  #pragma unroll
  for(int o=32;o;o>>=1) v = fminf(v,__shfl_xor(v,o));
  return v;
}
__device__ __forceinline__ float blk_sum256(float v){
  __shared__ float sm[4];
  v = wave_sum(v);
  __syncthreads();
  if((threadIdx.x&63)==0) sm[threadIdx.x>>6]=v;
  __syncthreads();
  return sm[0]+sm[1]+sm[2]+sm[3];
}
__device__ __forceinline__ float blk_min256(float v){
  __shared__ float sm[4];
  v = wave_min(v);
  __syncthreads();
  if((threadIdx.x&63)==0) sm[threadIdx.x>>6]=v;
  __syncthreads();
  return fminf(fminf(sm[0],sm[1]),fminf(sm[2],sm[3]));
}
__device__ __forceinline__ float blk_max256(float v){
  __shared__ float sm[4];
  v = wave_max(v);
  __syncthreads();
  if((threadIdx.x&63)==0) sm[threadIdx.x>>6]=v;
  __syncthreads();
  return fmaxf(fmaxf(sm[0],sm[1]),fmaxf(sm[2],sm[3]));
}

// =================== 256x256 4-phase GEMM (T2+T3+T4+T5) ====================
// 512 thr (8 waves 2Mx4N), BK=64, 2 LDS K-tile buffers (128KB).
// Per tile: {stage A x4; vmcnt(4); bar} then 4 phases with register reuse:
//  P1: read A(QR0)8 + B(QC0)4 | stage B x2 -> bar,lgk0 -> MFMA(0,0) -> bar
//  P2: read B(QC1)4           | stage B x2 -> bar,lgk0 -> MFMA(0,1) -> bar
//  P3: read A(QR1)8                        -> bar,lgk0 -> MFMA(1,0) -> bar
//  P4: (no reads)                                      -> MFMA(1,1) -> bar
// Swizzle: granule(16B) ^= row&7 on read; source col pre-swizzled (involution).
// MODE 1 (gram): upper-triangle blocks only + NT store + min/max atomics.

#define STG_A(bb,HH,Q,KT) __builtin_amdgcn_global_load_lds( \
  (__attribute__((address_space(1))) void*)(gAr + (size_t)((HH)*128+(Q)*64)*K + (size_t)(KT)*64), \
  (__attribute__((address_space(3))) void*)(lds + (bb)*16384 + (HH)*8192 + (Q)*4096 + (wid<<9)), 16, 0, 0)
#define STG_B(bb,HH,Q,KT) __builtin_amdgcn_global_load_lds( \
  (__attribute__((address_space(1))) void*)(gBr + (size_t)((HH)*128+(Q)*64)*K + (size_t)(KT)*64), \
  (__attribute__((address_space(3))) void*)(lds + 32768 + (bb)*16384 + (HH)*8192 + (Q)*4096 + (wid<<9)), 16, 0, 0)

#define RDX(base,row,kh) (*(const s16x8*)(lds + (base) + (row)*64 + (((((kh)<<2)|(lane>>4)) ^ ((row)&7))<<3)))

#define MM(i,j,x,y) acc[i][j]=__builtin_amdgcn_mfma_f32_16x16x32_bf16(x,y,acc[i][j],0,0,0)

#define BAR_WAIT() do{ __builtin_amdgcn_s_barrier(); \
  asm volatile("s_waitcnt lgkmcnt(0)" ::: "memory"); \
  __builtin_amdgcn_sched_barrier(0); }while(0)

template<int MODE>
__global__ __launch_bounds__(512,2) void gemm256(
  const u16* __restrict__ A, const u16* __restrict__ Bt,
  int M, int Nc, int K,
  u16* __restrict__ Cb, unsigned* __restrict__ mmx)
{
  __shared__ __align__(16) u16 lds[65536];   // 128 KB: 2 buf x (A 32K + B 32K)
  const int tid = threadIdx.x;
  const int wid = tid>>6, lane = tid&63;
  const int wm = wid>>2, wn = wid&3;
  const int lr = lane&15;

  const int gx = gridDim.x;
  int lid = blockIdx.y*gx + blockIdx.x;
  const int nwg = gx*gridDim.y;
  if ((nwg & 7) == 0){ const int chunk = nwg>>3; lid = (lid&7)*chunk + (lid>>3); }
  const int m0 = (lid/gx)<<8, n0 = (lid%gx)<<8;
  if (MODE==1 && m0 > n0) return;            // symmetric: upper triangle only

  const int Klen = K/gridDim.z;
  const int kbeg = blockIdx.z*Klen;
  const int NT = Klen>>6;
  const int kt0 = kbeg>>6;

  // staging: per instr 64 rows x 128B; LDS dest linear; SOURCE granule swizzled.
  const int srow = (wid<<3) + (lane>>3);                 // 0..63
  const int scol = (((lane&7) ^ ((lane>>3)&7))<<3);      // involution w/ read
  const u16* gAr = A  + (size_t)(m0 + srow)*K + scol;
  const u16* gBr = Bt + (size_t)(n0 + srow)*K + scol;

  f32x4 acc[8][4] = {};

  // prologue: tile 0 -> buffer 0
  STG_A(0,0,0,kt0); STG_A(0,0,1,kt0); STG_A(0,1,0,kt0); STG_A(0,1,1,kt0);
  STG_B(0,0,0,kt0); STG_B(0,0,1,kt0); STG_B(0,1,0,kt0); STG_B(0,1,1,kt0);

  for (int t=0; t<NT; ++t){
    const int cbuf = t&1, nbuf = cbuf^1;
    const int abase = cbuf*16384, bbase = 32768 + cbuf*16384;
    const int ktn = kt0 + t + 1;
    const bool more = (t+1 < NT);
    if (more){
      STG_A(nbuf,0,0,ktn); STG_A(nbuf,0,1,ktn); STG_A(nbuf,1,0,ktn); STG_A(nbuf,1,1,ktn);
      asm volatile("s_waitcnt vmcnt(4)" ::: "memory");   // tile t fully landed
    } else {
      asm volatile("s_waitcnt vmcnt(0)" ::: "memory");
    }
    __builtin_amdgcn_sched_barrier(0);
    __builtin_amdgcn_s_barrier();

    s16x8 a00,a01,a10,a11,a20,a21,a30,a31;   // A frags: a{mi}{kh}
    s16x8 b00,b01,b10,b11;                   // B QC=0:  b{ni}{kh}
    s16x8 c00,c01,c10,c11;                   // B QC=1

    // ---- P1: A(QR0) + B(QC0) reads, stage B half 0, MFMA (0,0)
    { int r0=(wm<<7)+lr;
      a00=RDX(abase,r0,0);    a01=RDX(abase,r0,1);
      a10=RDX(abase,r0+16,0); a11=RDX(abase,r0+16,1);
      a20=RDX(abase,r0+32,0); a21=RDX(abase,r0+32,1);
      a30=RDX(abase,r0+48,0); a31=RDX(abase,r0+48,1);
      int s0=(wn<<6)+lr;
      b00=RDX(bbase,s0,0);    b01=RDX(bbase,s0,1);
      b10=RDX(bbase,s0+16,0); b11=RDX(bbase,s0+16,1); }
    if (more){ STG_B(nbuf,0,0,ktn); STG_B(nbuf,0,1,ktn); }
    BAR_WAIT();
    __builtin_amdgcn_s_setprio(1);
    MM(0,0,a00,b00); MM(0,0,a01,b01); MM(1,0,a10,b00); MM(1,0,a11,b01);
    MM(2,0,a20,b00); MM(2,0,a21,b01); MM(3,0,a30,b00); MM(3,0,a31,b01);
    MM(0,1,a00,b10); MM(0,1,a01,b11); MM(1,1,a10,b10); MM(1,1,a11,b11);
    MM(2,1,a20,b10); MM(2,1,a21,b11); MM(3,1,a30,b10); MM(3,1,a31,b11);
    __builtin_amdgcn_s_setprio(0);
    __builtin_amdgcn_s_barrier();

    // ---- P2: B(QC1) reads, stage B half 1, MFMA (0,1)
    { int s1=(wn<<6)+32+lr;
      c00=RDX(bbase,s1,0);    c01=RDX(bbase,s1,1);
      c10=RDX(bbase,s1+16,0); c11=RDX(bbase,s1+16,1); }
    if (more){ STG_B(nbuf,1,0,ktn); STG_B(nbuf,1,1,ktn); }
    BAR_WAIT();
    __builtin_amdgcn_s_setprio(1);
    MM(0,2,a00,c00); MM(0,2,a01,c01); MM(1,2,a10,c00); MM(1,2,a11,c01);
    MM(2,2,a20,c00); MM(2,2,a21,c01); MM(3,2,a30,c00); MM(3,2,a31,c01);
    MM(0,3,a00,c10); MM(0,3,a01,c11); MM(1,3,a10,c10); MM(1,3,a11,c11);
    MM(2,3,a20,c10); MM(2,3,a21,c11); MM(3,3,a30,c10); MM(3,3,a31,c11);
    __builtin_amdgcn_s_setprio(0);
    __builtin_amdgcn_s_barrier();

    // ---- P3: A(QR1) reads (overwrite a*), MFMA (1,0) with live b*
    { int r1=(wm<<7)+64+lr;
      a00=RDX(abase,r1,0);    a01=RDX(abase,r1,1);
      a10=RDX(abase,r1+16,0); a11=RDX(abase,r1+16,1);
      a20=RDX(abase,r1+32,0); a21=RDX(abase,r1+32,1);
      a30=RDX(abase,r1+48,0); a31=RDX(abase,r1+48,1); }
    BAR_WAIT();
    __builtin_amdgcn_s_setprio(1);
    MM(4,0,a00,b00); MM(4,0,a01,b01); MM(5,0,a10,b00); MM(5,0,a11,b01);
    MM(6,0,a20,b00); MM(6,0,a21,b01); MM(7,0,a30,b00); MM(7,0,a31,b01);
    MM(4,1,a00,b10); MM(4,1,a01,b11); MM(5,1,a10,b10); MM(5,1,a11,b11);
    MM(6,1,a20,b10); MM(6,1,a21,b11); MM(7,1,a30,b10); MM(7,1,a31,b11);
    __builtin_amdgcn_s_setprio(0);
    __builtin_amdgcn_s_barrier();

    // ---- P4: MFMA (1,1) with live a*, c*
    __builtin_amdgcn_s_setprio(1);
    MM(4,2,a00,c00); MM(4,2,a01,c01); MM(5,2,a10,c00); MM(5,2,a11,c01);
    MM(6,2,a20,c00); MM(6,2,a21,c01); MM(7,2,a30,c00); MM(7,2,a31,c01);
    MM(4,3,a00,c10); MM(4,3,a01,c11); MM(5,3,a10,c10); MM(5,3,a11,c11);
    MM(6,3,a20,c10); MM(6,3,a21,c11); MM(7,3,a30,c10); MM(7,3,a31,c11);
    __builtin_amdgcn_s_setprio(0);
    __builtin_amdgcn_s_barrier();
  }

  float tmin=3.0e38f, tmax=-3.0e38f;
  if (MODE==1){
    #pragma unroll
    for(int mi=0;mi<8;mi++)
      #pragma unroll
      for(int ni=0;ni<4;ni++){
        f32x4 v=acc[mi][ni];
        #pragma unroll
        for(int e=0;e<4;e++){ tmin=fminf(tmin,v[e]); tmax=fmaxf(tmax,v[e]); }
      }
  }

  // epilogue: 2 passes of 128 rows through LDS -> full-line stores
  __syncthreads();
  #pragma unroll
  for(int p=0;p<2;p++){
    if (wm==p){
      #pragma unroll
      for(int mi=0;mi<8;mi++)
        #pragma unroll
        for(int ni=0;ni<4;ni++){
          f32x4 v=acc[mi][ni];
          int rl=(mi<<4)+((lane>>4)<<2);
          int cl=(wn<<6)+(ni<<4)+lr;
          #pragma unroll
          for(int e=0;e<4;e++) lds[(rl+e)*256+cl]=f2b(v[e]);
        }
    }
    __syncthreads();
    u16* Cp = (MODE==0) ? (Cb + (size_t)blockIdx.z*M*Nc) : Cb;
    #pragma unroll
    for(int it=0;it<8;it++){
      int idx=(it<<12)+(tid<<3);
      int row=idx>>8, col=idx&255;
      s16x8 v=*(const s16x8*)(lds+idx);
      if (MODE==1)
        __builtin_nontemporal_store(v,(s16x8*)(Cp+(size_t)(m0+(p<<7)+row)*Nc+n0+col));
      else
        *(s16x8*)(Cp+(size_t)(m0+(p<<7)+row)*Nc+n0+col)=v;
    }
    __syncthreads();
  }

  if (MODE==1){
    tmin=wave_min(tmin); tmax=wave_max(tmax);
    __shared__ float rmn[8], rmx[8];
    if(lane==0){ rmn[wid]=tmin; rmx[wid]=tmax; }
    __syncthreads();
    if(tid==0){
      float mn=rmn[0], mx=rmx[0];
      #pragma unroll
      for(int i=1;i<8;i++){ mn=fminf(mn,rmn[i]); mx=fmaxf(mx,rmx[i]); }
      atomicMin(mmx+0,fkey(mn));
      atomicMax(mmx+1,fkey(mx));
    }
  }
}

// copy strictly-upper 256-blocks of C[N][N] to lower, transposed (32x32 tiles)
__global__ __launch_bounds__(256) void mirror_lower(u16* __restrict__ C)
{
  int c0 = blockIdx.x<<5, r0 = blockIdx.y<<5;   // source tile (upper)
  if ((r0>>8) >= (c0>>8)) return;               // only strictly-upper 256-blocks
  __shared__ u16 t[32][33];
  int tx = threadIdx.x&31, ty = threadIdx.x>>5;
  #pragma unroll
  for(int i=0;i<32;i+=8) t[ty+i][tx] = C[(size_t)(r0+ty+i)*N_ + c0+tx];
  __syncthreads();
  #pragma unroll
  for(int i=0;i<32;i+=8)
    __builtin_nontemporal_store(t[tx][ty+i], C + (size_t)(c0+ty+i)*N_ + r0+tx);
}

// ---------------- 128x128 GEMM (skinny / small-K products) -----------------
template<int VW> __device__ __forceinline__ void waitv(){
  if constexpr(VW==8) asm volatile("s_waitcnt vmcnt(8)" ::: "memory");
  else if constexpr(VW==4) asm volatile("s_waitcnt vmcnt(4)" ::: "memory");
  else asm volatile("s_waitcnt vmcnt(0)" ::: "memory");
}

#define STG4(bb,k0) do{ \
  __builtin_amdgcn_global_load_lds((__attribute__((address_space(1))) void*)(gA0+(k0)), (__attribute__((address_space(3))) void*)(lds + (bb)*4096 + (wid<<9)),        16, 0, 0); \
  __builtin_amdgcn_global_load_lds((__attribute__((address_space(1))) void*)(gA1+(k0)), (__attribute__((address_space(3))) void*)(lds + (bb)*4096 + 2048 + (wid<<9)), 16, 0, 0); \
  __builtin_amdgcn_global_load_lds((__attribute__((address_space(1))) void*)(gB0+(k0)), (__attribute__((address_space(3))) void*)(lds + 12288 + (bb)*4096 + (wid<<9)),        16, 0, 0); \
  __builtin_amdgcn_global_load_lds((__attribute__((address_space(1))) void*)(gB1+(k0)), (__attribute__((address_space(3))) void*)(lds + 12288 + (bb)*4096 + 2048 + (wid<<9)), 16, 0, 0); \
}while(0)

template<int MODE>
__global__ __launch_bounds__(256) void gemm_bt(
  const u16* __restrict__ A, const u16* __restrict__ Bt,
  int M, int Nc, int K,
  u16* __restrict__ Cb, unsigned* __restrict__ mmx,
  const unsigned* __restrict__ gate)
{
  if (gate && gate[2] <= SPARSE_MAX) return;
  __shared__ __align__(16) u16 lds[3*4096*2];   // 48 KB
  const int tid = threadIdx.x;
  const int wid = tid>>6, lane = tid&63;

  const int gx = gridDim.x;
  int lid = blockIdx.y*gx + blockIdx.x;
  const int nwg = gx*gridDim.y;
  if ((nwg & 7) == 0) {
    const int chunk = nwg >> 3;
    lid = (lid & 7)*chunk + (lid >> 3);
  }
  const int m0 = (lid/gx)<<7, n0 = (lid%gx)<<7;
  const int wr = wid>>1, wc = wid&1;

  const int Klen = K / gridDim.z;
  const int kbeg = blockIdx.z * Klen;

  const int srow = (wid<<4) + (lane>>2);
  const int scol = (lane&3)<<3;
  const u16* gA0 = A  + (size_t)(m0+srow   )*K + scol;
  const u16* gA1 = A  + (size_t)(m0+srow+64)*K + scol;
  const u16* gB0 = Bt + (size_t)(n0+srow   )*K + scol;
  const u16* gB1 = Bt + (size_t)(n0+srow+64)*K + scol;

  f32x4 acc[4][4] = {};
  const int lr = lane&15, lk = (lane>>4)<<3;

  const int NIT = Klen>>5;   // >= 3 required
  STG4(0, kbeg);
  STG4(1, kbeg+32);
  STG4(2, kbeg+64);

  for (int it=0; it<NIT-2; ++it){
    const int b = it - (it/3)*3;
    waitv<8>();
    __builtin_amdgcn_s_barrier();
    const u16* baseA = lds + b*4096;
    const u16* baseB = lds + 12288 + b*4096;
    s16x8 af[4], bfr[4];
    #pragma unroll
    for(int m=0;m<4;m++) af[m]  = *(const s16x8*)(baseA + ((wr<<6)+(m<<4)+lr)*32 + lk);
    #pragma unroll
    for(int n=0;n<4;n++) bfr[n] = *(const s16x8*)(baseB + ((wc<<6)+(n<<4)+lr)*32 + lk);
    asm volatile("s_waitcnt lgkmcnt(0)" ::: "memory");
    __builtin_amdgcn_sched_barrier(0);
    __builtin_amdgcn_s_barrier();
    if (it+3 < NIT) STG4(b, kbeg + ((it+3)<<5));
    #pragma unroll
    for(int m=0;m<4;m++)
      #pragma unroll
      for(int n=0;n<4;n++)
        acc[m][n] = __builtin_amdgcn_mfma_f32_16x16x32_bf16(af[m], bfr[n], acc[m][n], 0,0,0);
  }
  {
    const int it = NIT-2; const int b = it - (it/3)*3;
    waitv<4>();
    __builtin_amdgcn_s_barrier();
    const u16* baseA = lds + b*4096;
    const u16* baseB = lds + 12288 + b*4096;
    s16x8 af[4], bfr[4];
    #pragma unroll
    for(int m=0;m<4;m++) af[m]  = *(const s16x8*)(baseA + ((wr<<6)+(m<<4)+lr)*32 + lk);
    #pragma unroll
    for(int n=0;n<4;n++) bfr[n] = *(const s16x8*)(baseB + ((wc<<6)+(n<<4)+lr)*32 + lk);
    #pragma unroll
    for(int m=0;m<4;m++)
      #pragma unroll
      for(int n=0;n<4;n++)
        acc[m][n] = __builtin_amdgcn_mfma_f32_16x16x32_bf16(af[m], bfr[n], acc[m][n], 0,0,0);
  }
  {
    const int it = NIT-1; const int b = it - (it/3)*3;
    waitv<0>();
    __builtin_amdgcn_s_barrier();
    const u16* baseA = lds + b*4096;
    const u16* baseB = lds + 12288 + b*4096;
    s16x8 af[4], bfr[4];
    #pragma unroll
    for(int m=0;m<4;m++) af[m]  = *(const s16x8*)(baseA + ((wr<<6)+(m<<4)+lr)*32 + lk);
    #pragma unroll
    for(int n=0;n<4;n++) bfr[n] = *(const s16x8*)(baseB + ((wc<<6)+(n<<4)+lr)*32 + lk);
    #pragma unroll
    for(int m=0;m<4;m++)
      #pragma unroll
      for(int n=0;n<4;n++)
        acc[m][n] = __builtin_amdgcn_mfma_f32_16x16x32_bf16(af[m], bfr[n], acc[m][n], 0,0,0);
  }

  __syncthreads();
  u16* lC = lds;
  {
    const int rb_l = (wr<<6) + ((lane>>4)<<2);
    const int cb_l = (wc<<6) + lr;
    #pragma unroll
    for(int m=0;m<4;m++)
      #pragma unroll
      for(int n=0;n<4;n++){
        f32x4 v = acc[m][n];
        #pragma unroll
        for(int e=0;e<4;e++)
          lC[(rb_l+(m<<4)+e)*128 + cb_l+(n<<4)] = f2b(v[e]);
      }
  }
  __syncthreads();
  u16* Cp = Cb + (size_t)blockIdx.z * M * Nc;
  #pragma unroll
  for(int q=0;q<8;q++){
    int c = (q<<8) + tid;
    int r = c>>4, cc = (c&15)<<3;
    *(s16x8*)(Cp + (size_t)(m0+r)*Nc + n0 + cc) = *(const s16x8*)(lC + r*128 + cc);
  }
  (void)mmx;
}

// src [R][C] fp32 -> dst [C][R] bf16   (weight prep)
__global__ __launch_bounds__(256) void transpose_cast(
  const float* __restrict__ src, u16* __restrict__ dst, int R, int C)
{
  __shared__ float t[32][33];
  int c0 = blockIdx.x<<5, r0 = blockIdx.y<<5;
  int tx = threadIdx.x&31, ty = threadIdx.x>>5;
  #pragma unroll
  for(int i=0;i<32;i+=8) t[ty+i][tx] = src[(size_t)(r0+ty+i)*C + c0+tx];
  __syncthreads();
  #pragma unroll
  for(int i=0;i<32;i+=8) dst[(size_t)(c0+ty+i)*R + r0+tx] = f2b(t[tx][ty+i]);
}

// dst[C][R] bf16 = transpose( sum_p bf16_plane_p [R][C] ); gated (dense path)
__global__ __launch_bounds__(256) void transpose_sum_bf(
  const u16* __restrict__ src, size_t pstr, int nsp,
  u16* __restrict__ dst, int R, int C, const unsigned* __restrict__ gate)
{
  if (gate && gate[2] <= SPARSE_MAX) return;
  __shared__ float t[32][33];
  int c0 = blockIdx.x<<5, r0 = blockIdx.y<<5;
  int tx = threadIdx.x&31, ty = threadIdx.x>>5;
  #pragma unroll
  for(int i=0;i<32;i+=8){
    float v = 0;
    for(int p=0;p<nsp;p++)
      v += b2f(src[(size_t)p*pstr + (size_t)(r0+ty+i)*C + c0+tx]);
    t[ty+i][tx] = v;
  }
  __syncthreads();
  #pragma unroll
  for(int i=0;i<32;i+=8) dst[(size_t)(c0+ty+i)*R + r0+tx] = f2b(t[tx][ty+i]);
}

__global__ __launch_bounds__(256) void prep_x(const float* __restrict__ x,
  u16* __restrict__ xb, u16* __restrict__ xnb)
{
  int row = blockIdx.x, t = threadIdx.x;
  const float* p = x + (size_t)row*L_ + (t<<2);
  f32x4 v = *(const f32x4*)p;
  float ss = v[0]*v[0]+v[1]*v[1]+v[2]*v[2]+v[3]*v[3];
  float tot = blk_sum256(ss);
  float inv = 1.0f/fmaxf(sqrtf(tot), 1e-12f);
  u16* pb = xb  + (size_t)row*L_ + (t<<2);
  u16* pn = xnb + (size_t)row*L_ + (t<<2);
  #pragma unroll
  for(int k=0;k<4;k++){ pb[k]=f2b(v[k]); pn[k]=f2b(v[k]*inv); }
}

// fused-projection epilogue: a at cols [0,256), b at [256,512) of [N,1536] planes
__global__ __launch_bounds__(256) void attn_epi(const u16* __restrict__ SPA,
  size_t pstr, int nsp,
  const float* __restrict__ ba, const float* __restrict__ bb,
  const float* __restrict__ wc, const float* __restrict__ bc,
  float* __restrict__ agg, float* __restrict__ s)
{
  int row = (blockIdx.x<<2) + (threadIdx.x>>6);
  int lane = threadIdx.x&63;
  float a[4]={0,0,0,0}, b[4]={0,0,0,0};
  for(int p=0;p<nsp;p++){
    s16x4 ua = *(const s16x4*)(SPA + (size_t)p*pstr + (size_t)row*1536 + (lane<<2));
    s16x4 ub = *(const s16x4*)(SPA + (size_t)p*pstr + (size_t)row*1536 + 256 + (lane<<2));
    #pragma unroll
    for(int j=0;j<4;j++){ a[j]+=b2f((u16)ua[j]); b[j]+=b2f((u16)ub[j]); }
  }
  float acc=0;
  #pragma unroll
  for(int j=0;j<4;j++){
    int h = (lane<<2)+j;
    float tv = tanhf(a[j]+ba[h]);
    float sg = 1.0f/(1.0f+expf(-(b[j]+bb[h])));
    acc += tv*sg*wc[h];
  }
  acc = wave_sum(acc);
  if(lane==0){
    float v = acc + bc[0];
    agg[row]=v;
    s[row]=1.0f/(1.0f+expf(-v));
  }
}

__global__ __launch_bounds__(256) void s_stats(const float* __restrict__ s, float* __restrict__ sc){
  int t=threadIdx.x;
  float sum=0, mn=3e38f, mx=-3e38f;
  for(int i=t;i<N_;i+=256){ float v=s[i]; sum+=v; mn=fminf(mn,v); mx=fmaxf(mx,v); }
  float S=blk_sum256(sum);
  float MN=blk_min256(mn);
  float MX=blk_max256(mx);
  if(t==0){ sc[0]=S; sc[1]=MN; sc[2]=MX; }
}

__global__ __launch_bounds__(256) void aw_write(const float* __restrict__ maps, const float* __restrict__ s,
  const float* __restrict__ sc, u16* __restrict__ awb)
{
  int i = blockIdx.x, t = threadIdx.x;
  float smin = sc[1], smax = sc[2];
  float mn = smin*smin, mx = smax*smax;
  float beta = 0.6f/(mx-mn);
  float c1 = 0.4f - beta*mn;
  float si = s[i];
  const float* mrow = maps + (size_t)i*N_;
  float mv[24];
  float part = 0;
  #pragma unroll
  for(int q=0;q<24;q++){
    int j = t + (q<<8);
    mv[q] = c1 + beta*si*s[j] + mrow[j];
    part += mv[q];
  }
  float r = blk_sum256(part);
  float inv = 1.0f/fmaxf(r, 1e-12f);
  u16* orow = awb + (size_t)i*N_;
  #pragma unroll
  for(int q=0;q<24;q++)
    __builtin_nontemporal_store(f2b(mv[q]*inv), orow + t + (q<<8));
}

// out = relu(LN( (sum_p Y_p)*rowscale + bias )).  Gated sparse: read Yalt.
__global__ __launch_bounds__(256) void ln_epi512(const u16* __restrict__ Y, size_t pstr, int nsp,
  int rs, int cbase,
  const float* __restrict__ ki,
  const float* __restrict__ bias, const float* __restrict__ g, const float* __restrict__ bn,
  u16* __restrict__ outb,
  const unsigned* __restrict__ gate, const u16* __restrict__ Yalt)
{
  const u16* src = Y; size_t ps = pstr; int np = nsp, rstride = rs, cb = cbase;
  if (gate && gate[2] <= SPARSE_MAX){ src = Yalt; ps = 0; np = 1; rstride = 512; cb = 0; }
  int row = (blockIdx.x<<2)+(threadIdx.x>>6);
  int lane = threadIdx.x&63;
  int c0 = lane<<3;
  float v[8] = {0,0,0,0,0,0,0,0};
  for(int p=0;p<np;p++){
    s16x8 u = *(const s16x8*)(src + (size_t)p*ps + (size_t)row*rstride + cb + c0);
    #pragma unroll
    for(int j=0;j<8;j++) v[j] += b2f((u16)u[j]);
  }
  float scale = ki ? (1.0f/ki[row]) : 1.0f;
  float sum=0, ssum=0;
  #pragma unroll
  for(int j=0;j<8;j++){ v[j] = v[j]*scale + bias[c0+j]; sum+=v[j]; ssum+=v[j]*v[j]; }
  sum = wave_sum(sum); ssum = wave_sum(ssum);
  float m = sum*(1.0f/D_);
  float var = ssum*(1.0f/D_) - m*m;
  float invsd = rsqrtf(var + 1e-5f);
  u16 ob[8];
  #pragma unroll
  for(int j=0;j<8;j++){
    float o = (v[j]-m)*invsd*g[c0+j] + bn[c0+j];
    o = fmaxf(o, 0.0f);
    ob[j] = f2b(o);
  }
  *(s16x8*)(outb + (size_t)row*D_ + c0) = *(s16x8*)ob;
}

__global__ __launch_bounds__(256) void bias_cast(const u16* __restrict__ Y, size_t pstr, int nsp,
  const float* __restrict__ b, u16* __restrict__ outb)
{
  size_t idx = ((size_t)blockIdx.x*256 + threadIdx.x)<<3;
  float v[8] = {0,0,0,0,0,0,0,0};
  for(int p=0;p<nsp;p++){
    s16x8 u = *(const s16x8*)(Y + (size_t)p*pstr + idx);
    #pragma unroll
    for(int j=0;j<8;j++) v[j] += b2f((u16)u[j]);
  }
  int c = (int)(idx & (D_-1));
  u16 ob[8];
  #pragma unroll
  for(int k=0;k<8;k++) ob[k] = f2b(v[k]+b[c+k]);
  *(s16x8*)(outb+idx) = *(s16x8*)ob;
}

__global__ void init_k(unsigned* mmx){ mmx[0]=0xFFFFFFFFu; mmx[1]=0u; mmx[2]=0u; }

// binarize in place + bitmap + per-row count + max-nnz + fused trans/z
__global__ __launch_bounds__(256) void binarize(u16* __restrict__ csb,
  unsigned* __restrict__ mmx, const float* __restrict__ agg,
  float* __restrict__ ki, float* __restrict__ z, u64* __restrict__ bm)
{
  int i = blockIdx.x, t = threadIdx.x;
  int lane = t&63, w = t>>6;
  float mn = funkey(mmx[0]), mx = funkey(mmx[1]);
  float th = mn + 0.5f*(mx-mn);
  u16* row = csb + (size_t)i*N_;
  u64* bmrow = bm + (size_t)i*96;
  float cnt = 0, dot = 0;
  #pragma unroll
  for(int q=0;q<24;q++){
    int j = t + (q<<8);
    bool on = b2f(row[j]) >= th;
    __builtin_nontemporal_store(on ? (u16)0x3F80 : (u16)0, row + j);
    u64 mask = __ballot(on);
    if(lane==0) bmrow[(q<<2)+w] = mask;
    if(on){ cnt += 1.0f; dot += agg[j]; }
  }
  float k = blk_sum256(cnt);
  float dt = blk_sum256(dot);
  if(t==0){
    ki[i] = k;
    float tr = dt/(k*sqrtf((float)N_));
    z[i] = 0.3f*tr + 0.7f*agg[i];
    atomicMax(mmx+2, (unsigned)(k+0.5f));
  }
}

// sparse adjacency apply: YS[i,:] = sum_{j: bit set} sum_p SP[p][j,:]
__global__ __launch_bounds__(256) void gather_rows(const u64* __restrict__ bm,
  const u16* __restrict__ SPp, size_t pstr, int nsp,
  const unsigned* __restrict__ gate, u16* __restrict__ YS)
{
  if (gate[2] > SPARSE_MAX) return;
  int i = blockIdx.x, t = threadIdx.x;
  __shared__ u64 wbuf[96];
  __shared__ u16 idx[SPARSE_MAX];
  __shared__ int nn_s;
  if (t < 96) wbuf[t] = bm[(size_t)i*96 + t];
  __syncthreads();
  if (t == 0){
    int nn = 0;
    for(int k=0;k<96;k++){
      u64 m = wbuf[k];
      while(m && nn < (int)SPARSE_MAX){
        int b = __ffsll((long long)m) - 1;
        m &= m - 1;
        idx[nn++] = (u16)((k<<6) + b);
      }
    }
    nn_s = nn;
  }
  __syncthreads();
  int nn = nn_s;
  float a0=0, a1=0;
  for(int k=0;k<nn;k++){
    size_t jb = (size_t)idx[k]*512;
    for(int p=0;p<nsp;p++){
      a0 += b2f(SPp[p*pstr + jb + t]);
      a1 += b2f(SPp[p*pstr + jb + t + 256]);
    }
  }
  YS[(size_t)i*512 + t]       = f2b(a0);
  YS[(size_t)i*512 + t + 256] = f2b(a1);
}

__global__ __launch_bounds__(1024) void softmax_prep(const float* __restrict__ z,
  float* __restrict__ e, float* __restrict__ sexp)
{
  int t = threadIdx.x;
  __shared__ float sm[16];
  float mx=-3e38f;
  for(int i=t;i<N_;i+=1024) mx=fmaxf(mx,z[i]);
  mx = wave_max(mx);
  if((t&63)==0) sm[t>>6]=mx;
  __syncthreads();
  float zm = sm[0];
  #pragma unroll
  for(int w=1;w<16;w++) zm=fmaxf(zm,sm[w]);
  __syncthreads();
  float sum=0;
  for(int i=t;i<N_;i+=1024){ float ee=expf(z[i]-zm); e[i]=ee; sum+=ee; }
  sum = wave_sum(sum);
  if((t&63)==0) sm[t>>6]=sum;
  __syncthreads();
  if(t==0){ float S=0; for(int w=0;w<16;w++) S+=sm[w]; *sexp=S; }
}

__global__ __launch_bounds__(256) void pooled_partial(const float* __restrict__ e,
  const u16* __restrict__ g2b, const u16* __restrict__ g1b, float* __restrict__ part)
{
  int b = blockIdx.x, t = threadIdx.x;
  float a0=0,a1=0,a2=0,a3=0;
  for(int r=0;r<24;r++){
    int row = b*24+r;
    float w = e[row];
    a0 += w * b2f(g2b[(size_t)row*D_ + t]);
    a1 += w * b2f(g2b[(size_t)row*D_ + t+256]);
    a2 += w * b2f(g1b[(size_t)row*D_ + t]);
    a3 += w * b2f(g1b[(size_t)row*D_ + t+256]);
  }
  part[(size_t)b*1024 + t]      = a0;
  part[(size_t)b*1024 + t+256]  = a1;
  part[(size_t)b*1024 + t+512]  = a2;
  part[(size_t)b*1024 + t+768]  = a3;
}

__global__ __launch_bounds__(1024) void final_k(const float* __restrict__ part, const float* __restrict__ sexp,
  const float* __restrict__ lng, const float* __restrict__ lnb,
  const float* __restrict__ clsw, float* __restrict__ out)
{
  int t = threadIdx.x;
  __shared__ float red[16];
  __shared__ float smv[1024];
  __shared__ float lgs[4];
  float p=0;
  for(int b=0;b<256;b++) p += part[b*1024 + t];
  p /= sexp[0];
  float w = wave_sum(p);
  if((t&63)==0) red[t>>6]=w;
  __syncthreads();
  float tot=0;
  #pragma unroll
  for(int i2=0;i2<16;i2++) tot+=red[i2];
  float m = tot*(1.0f/1024.0f);
  __syncthreads();
  float d = p-m;
  w = wave_sum(d*d);
  if((t&63)==0) red[t>>6]=w;
  __syncthreads();
  tot=0;
  #pragma unroll
  for(int i2=0;i2<16;i2++) tot+=red[i2];
  float var = tot*(1.0f/1024.0f);
  float y = d*rsqrtf(var+1e-5f)*lng[t] + lnb[t];
  smv[t]=y;
  __syncthreads();
  if(t<4){
    float lg=0;
    for(int j=0;j<1024;j++) lg += smv[j]*clsw[j*4+t];
    lgs[t]=lg;
  }
  __syncthreads();
  if(t==0){
    float h[4];
    int am=0; float best=lgs[0];
    #pragma unroll
    for(int c2=0;c2<4;c2++){ h[c2]=1.0f/(1.0f+expf(-lgs[c2])); if(lgs[c2]>best){best=lgs[c2];am=c2;} }
    float sv=1.0f;
    #pragma unroll
    for(int c2=0;c2<4;c2++){ out[c2]=h[c2]; sv*=(1.0f-h[c2]); out[4+c2]=sv; }
    out[8]=(float)am;
  }
}

extern "C" void kernel_launch(void* const* d_in, const int* in_sizes, int n_in,
                              void* d_out, int out_size, void* d_ws, size_t ws_size,
                              hipStream_t stream)
{
  const float* x_path =(const float*)d_in[0];
  const float* maps   =(const float*)d_in[1];
  const float* nl0_w1 =(const float*)d_in[2];
  const float* nl0_b1 =(const float*)d_in[3];
  const float* nl0_g  =(const float*)d_in[4];
  const float* nl0_bn =(const float*)d_in[5];
  const float* nl0_w2 =(const float*)d_in[6];
  const float* nl0_b2 =(const float*)d_in[7];
  const float* nl1_w1 =(const float*)d_in[8];
  const float* nl1_b1 =(const float*)d_in[9];
  const float* nl1_g  =(const float*)d_in[10];
  const float* nl1_bn =(const float*)d_in[11];
  const float* nl1_w2 =(const float*)d_in[12];
  const float* nl1_b2 =(const float*)d_in[13];
  const float *gw[6], *gb[6], *gg[6], *gbn[6];   // gc0,gc1,gc2,ga0,ga1,ga2
  for(int l=0;l<6;l++){
    gw[l]  = (const float*)d_in[14+l*4+0];
    gb[l]  = (const float*)d_in[14+l*4+1];
    gg[l]  = (const float*)d_in[14+l*4+2];
    gbn[l] = (const float*)d_in[14+l*4+3];
  }
  const float* attn_wa=(const float*)d_in[38];
  const float* attn_ba=(const float*)d_in[39];
  const float* attn_wb=(const float*)d_in[40];
  const float* attn_bb=(const float*)d_in[41];
  const float* attn_wc=(const float*)d_in[42];
  const float* attn_bc=(const float*)d_in[43];
  const float* cls_w  =(const float*)d_in[44];
  const float* ln_g   =(const float*)d_in[45];
  const float* ln_b   =(const float*)d_in[46];

  char* ws=(char*)d_ws;
  size_t off=0;
  auto alc=[&](size_t b)->char*{ char* p=ws+off; off=(off+b+255)&~(size_t)255; return p; };
  u16* BIG = (u16*)alc((size_t)N_*N_*2);          // aw, then cs/binary (time-shared)
  u16* XB  = (u16*)alc((size_t)N_*L_*2);
  u16* XNB = (u16*)alc((size_t)N_*L_*2);
  u16* WT_proj=(u16*)alc((size_t)1536*L_*2);      // [wa;wb;nl0w1;nl1w1] transposed
  u16* WT_nl0w2=(u16*)alc((size_t)D_*D_*2);
  u16* WT_nl1w2=(u16*)alc((size_t)D_*D_*2);
  u16* WT_g[6];
  for(int l=0;l<6;l++) WT_g[l]=(u16*)alc((size_t)D_*D_*2);
  u16* SP = (u16*)alc((size_t)2*N_*1536*2);       // split planes (max: proj SK=2)
  u16* XWT=(u16*)alc((size_t)D_*N_*2);
  u16* XA0=(u16*)alc((size_t)N_*D_*2);
  u16* XA1=(u16*)alc((size_t)N_*D_*2);
  u16* X0B=(u16*)alc((size_t)N_*D_*2);
  u16* X1B=(u16*)alc((size_t)N_*D_*2);
  u16* YS =(u16*)alc((size_t)N_*D_*2);
  u64* BM =(u64*)alc((size_t)N_*96*8);
  float* PART=(float*)alc((size_t)256*1024*4);
  float* AGG=(float*)alc(N_*4);
  float* SS =(float*)alc(N_*4);
  float* KI =(float*)alc(N_*4);
  float* Z  =(float*)alc(N_*4);
  float* E  =(float*)alc(N_*4);
  float* SC =(float*)alc(256);
  unsigned* MMX=(unsigned*)alc(256);
  float* SEXP=(float*)alc(256);

  const size_t PS_D = (size_t)N_*D_;      // 512-col plane stride
  const size_t PS_P = (size_t)N_*1536;    // proj plane stride

  init_k<<<1,1,0,stream>>>(MMX);
  prep_x<<<N_,256,0,stream>>>(x_path, XB, XNB);

  // weight prep
  transpose_cast<<<dim3(H_/32, L_/32),256,0,stream>>>(attn_wa, WT_proj,                   L_, H_);
  transpose_cast<<<dim3(H_/32, L_/32),256,0,stream>>>(attn_wb, WT_proj + (size_t)256*L_,  L_, H_);
  transpose_cast<<<dim3(D_/32, L_/32),256,0,stream>>>(nl0_w1,  WT_proj + (size_t)512*L_,  L_, D_);
  transpose_cast<<<dim3(D_/32, L_/32),256,0,stream>>>(nl1_w1,  WT_proj + (size_t)1024*L_, L_, D_);
  transpose_cast<<<dim3(D_/32, D_/32),256,0,stream>>>(nl0_w2, WT_nl0w2, D_, D_);
  transpose_cast<<<dim3(D_/32, D_/32),256,0,stream>>>(nl1_w2, WT_nl1w2, D_, D_);
  for(int l=0;l<6;l++)
    transpose_cast<<<dim3(D_/32, D_/32),256,0,stream>>>(gw[l], WT_g[l], D_, D_);

  // fused X projections: [a|b|h0|h1] = XB @ WT_proj^T  (SK=2)
  gemm_bt<0><<<dim3(1536/128, N_/128, 2),256,0,stream>>>(XB, WT_proj, N_, 1536, L_, SP, nullptr, nullptr);
  attn_epi<<<N_/4,256,0,stream>>>(SP, PS_P, 2, attn_ba, attn_bb, attn_wc, attn_bc, AGG, SS);
  s_stats<<<1,256,0,stream>>>(SS,SC);
  aw_write<<<N_,256,0,stream>>>(maps,SS,SC,BIG);

  ln_epi512<<<N_/4,256,0,stream>>>(SP,PS_P,2, 1536,1024, nullptr, nl1_b1,nl1_g,nl1_bn, XA1, nullptr,nullptr);
  ln_epi512<<<N_/4,256,0,stream>>>(SP,PS_P,2, 1536, 512, nullptr, nl0_b1,nl0_g,nl0_bn, XA0, nullptr,nullptr);

  gemm_bt<0><<<dim3(D_/128,N_/128,4),256,0,stream>>>(XA1, WT_nl1w2, N_,D_,D_, SP, nullptr, nullptr);
  bias_cast<<<(N_*D_/8)/256,256,0,stream>>>(SP,PS_D,4, nl1_b2, X1B);

  // ga chain (dense adjacency = BIG = aw) -- fixed 4-phase 256^2 GEMM
  {
    const u16* cur=X1B;
    for(int l=0;l<3;l++){
      int gi = 3+l;
      gemm_bt<0><<<dim3(D_/128,N_/128,4),256,0,stream>>>(cur, WT_g[gi], N_,D_,D_, SP, nullptr, nullptr);
      transpose_sum_bf<<<dim3(D_/32, N_/32),256,0,stream>>>(SP, PS_D, 4, XWT, N_, D_, nullptr);
      gemm256<0><<<dim3(D_/256, N_/256, 4),512,0,stream>>>(BIG, XWT, N_,D_,N_, SP, nullptr);
      u16* nxt = (l==0)? XA1 : (l==1)? YS : X1B;
      ln_epi512<<<N_/4,256,0,stream>>>(SP,PS_D,4, 512,0, nullptr, gb[gi],gg[gi],gbn[gi], nxt, nullptr,nullptr);
      cur = nxt;
    }
  }

  gemm_bt<0><<<dim3(D_/128,N_/128,4),256,0,stream>>>(XA0, WT_nl0w2, N_,D_,D_, SP, nullptr, nullptr);
  bias_cast<<<(N_*D_/8)/256,256,0,stream>>>(SP,PS_D,4, nl0_b2, X0B);

  // cosine gram (upper triangle) -> BIG + min/max; mirror to lower; binarize
  gemm256<1><<<dim3(N_/256, N_/256, 1),512,0,stream>>>(XNB, XNB, N_,N_,L_, BIG, MMX);
  mirror_lower<<<dim3(N_/32, N_/32),256,0,stream>>>(BIG);
  binarize<<<N_,256,0,stream>>>(BIG, MMX, AGG, KI, Z, BM);

  // gc chain: sparse gather path (gated) with dense GEMM fallback
  {
    const u16* cur=X0B;
    for(int l=0;l<3;l++){
      int gi = l;
      gemm_bt<0><<<dim3(D_/128,N_/128,4),256,0,stream>>>(cur, WT_g[gi], N_,D_,D_, SP, nullptr, nullptr);
      transpose_sum_bf<<<dim3(D_/32, N_/32),256,0,stream>>>(SP, PS_D, 4, XWT, N_, D_, MMX);
      gemm_bt<0><<<dim3(D_/128,N_/128,4),256,0,stream>>>(BIG, XWT, N_,D_,N_, SP, nullptr, MMX);
      gather_rows<<<N_,256,0,stream>>>(BM, SP, PS_D, 4, MMX, YS);
      u16* nxt = (l==0)? XA1 : (l==1)? XA0 : X0B;
      ln_epi512<<<N_/4,256,0,stream>>>(SP,PS_D,4, 512,0, KI, gb[gi],gg[gi],gbn[gi], nxt, MMX, YS);
      cur = nxt;
    }
  }

  // pooling + head
  softmax_prep<<<1,1024,0,stream>>>(Z,E,SEXP);
  pooled_partial<<<256,256,0,stream>>>(E,X1B,X0B,PART);
  final_k<<<1,1024,0,stream>>>(PART,SEXP,ln_g,ln_b,cls_w,(float*)d_out);

  (void)in_sizes;(void)n_in;(void)out_size;(void)ws_size;
}

// Round 8
// 877.493 us; speedup vs baseline: 1.0925x; 1.0110x over previous
//
#include <hip/hip_runtime.h>

#define N_ 6144
#define L_ 1024
#define D_ 512
#define H_ 256
#define SPARSE_MAX 64u

typedef unsigned short u16;
typedef unsigned long long u64;
typedef __attribute__((ext_vector_type(4))) float f32x4;
typedef __attribute__((ext_vector_type(8))) short s16x8;
typedef __attribute__((ext_vector_type(4))) short s16x4;

__device__ __forceinline__ u16 f2b(float f){
  unsigned u = __float_as_uint(f);
  u += 0x7FFFu + ((u >> 16) & 1u);
  return (u16)(u >> 16);
}
__device__ __forceinline__ float b2f(u16 h){ return __uint_as_float(((unsigned)h) << 16); }
__device__ __forceinline__ unsigned fkey(float f){
  unsigned u = __float_as_uint(f);
  return (u & 0x80000000u) ? ~u : (u | 0x80000000u);
}
__device__ __forceinline__ float funkey(unsigned k){
  unsigned u = (k & 0x80000000u) ? (k & 0x7FFFFFFFu) : ~k;
  return __uint_as_float(u);
}
__device__ __forceinline__ float wave_sum(float v){
  #pragma unroll
  for(int o=32;o;o>>=1) v += __shfl_xor(v,o);
  return v;
}
__device__ __forceinline__ float wave_max(float v){
  #pragma unroll
  for(int o=32;o;o>>=1) v = fmaxf(v,__shfl_xor(v,o));
  return v;
}
__device__ __forceinline__ float wave_min(float v){
  #pragma unroll
  for(int o=32;o;o>>=1) v = fminf(v,__shfl_xor(v,o));
  return v;
}
__device__ __forceinline__ float blk_sum256(float v){
  __shared__ float sm[4];
  v = wave_sum(v);
  __syncthreads();
  if((threadIdx.x&63)==0) sm[threadIdx.x>>6]=v;
  __syncthreads();
  return sm[0]+sm[1]+sm[2]+sm[3];
}
__device__ __forceinline__ float blk_min256(float v){
  __shared__ float sm[4];
  v = wave_min(v);
  __syncthreads();
  if((threadIdx.x&63)==0) sm[threadIdx.x>>6]=v;
  __syncthreads();
  return fminf(fminf(sm[0],sm[1]),fminf(sm[2],sm[3]));
}
__device__ __forceinline__ float blk_max256(float v){
  __shared__ float sm[4];
  v = wave_max(v);
  __syncthreads();
  if((threadIdx.x&63)==0) sm[threadIdx.x>>6]=v;
  __syncthreads();
  return fmaxf(fmaxf(sm[0],sm[1]),fmaxf(sm[2],sm[3]));
}

// ---------------- 128x128 GEMM: C[M,Nc] = A @ Bt^T (bf16) ------------------
// 3-buffer staging, XCD-chunked swizzle, LDS-bounce epilogue, split-K planes.
// MODE 0: write bf16 plane z.  gate!=null && sparse -> early exit.
// MODE 1 (gram): 128-tile upper-triangle only + NT store + min/max atomics.
template<int VW> __device__ __forceinline__ void waitv(){
  if constexpr(VW==8) asm volatile("s_waitcnt vmcnt(8)" ::: "memory");
  else if constexpr(VW==4) asm volatile("s_waitcnt vmcnt(4)" ::: "memory");
  else asm volatile("s_waitcnt vmcnt(0)" ::: "memory");
}

#define STG4(bb,k0) do{ \
  __builtin_amdgcn_global_load_lds((__attribute__((address_space(1))) void*)(gA0+(k0)), (__attribute__((address_space(3))) void*)(lds + (bb)*4096 + (wid<<9)),        16, 0, 0); \
  __builtin_amdgcn_global_load_lds((__attribute__((address_space(1))) void*)(gA1+(k0)), (__attribute__((address_space(3))) void*)(lds + (bb)*4096 + 2048 + (wid<<9)), 16, 0, 0); \
  __builtin_amdgcn_global_load_lds((__attribute__((address_space(1))) void*)(gB0+(k0)), (__attribute__((address_space(3))) void*)(lds + 12288 + (bb)*4096 + (wid<<9)),        16, 0, 0); \
  __builtin_amdgcn_global_load_lds((__attribute__((address_space(1))) void*)(gB1+(k0)), (__attribute__((address_space(3))) void*)(lds + 12288 + (bb)*4096 + 2048 + (wid<<9)), 16, 0, 0); \
}while(0)

template<int MODE>
__global__ __launch_bounds__(256) void gemm_bt(
  const u16* __restrict__ A, const u16* __restrict__ Bt,
  int M, int Nc, int K,
  u16* __restrict__ Cb, unsigned* __restrict__ mmx,
  const unsigned* __restrict__ gate)
{
  if (gate && gate[2] <= SPARSE_MAX) return;
  __shared__ __align__(16) u16 lds[3*4096*2];   // 48 KB
  const int tid = threadIdx.x;
  const int wid = tid>>6, lane = tid&63;

  const int gx = gridDim.x;
  int lid = blockIdx.y*gx + blockIdx.x;
  const int nwg = gx*gridDim.y;
  if ((nwg & 7) == 0) {
    const int chunk = nwg >> 3;
    lid = (lid & 7)*chunk + (lid >> 3);
  }
  const int m0 = (lid/gx)<<7, n0 = (lid%gx)<<7;
  if (MODE==1 && m0 > n0) return;              // symmetric gram: upper triangle
  const int wr = wid>>1, wc = wid&1;

  const int Klen = K / gridDim.z;
  const int kbeg = blockIdx.z * Klen;

  const int srow = (wid<<4) + (lane>>2);
  const int scol = (lane&3)<<3;
  const u16* gA0 = A  + (size_t)(m0+srow   )*K + scol;
  const u16* gA1 = A  + (size_t)(m0+srow+64)*K + scol;
  const u16* gB0 = Bt + (size_t)(n0+srow   )*K + scol;
  const u16* gB1 = Bt + (size_t)(n0+srow+64)*K + scol;

  f32x4 acc[4][4] = {};
  const int lr = lane&15, lk = (lane>>4)<<3;

  const int NIT = Klen>>5;   // >= 3 required (all launches satisfy)
  STG4(0, kbeg);
  STG4(1, kbeg+32);
  STG4(2, kbeg+64);

  for (int it=0; it<NIT-2; ++it){
    const int b = it - (it/3)*3;
    waitv<8>();
    __builtin_amdgcn_s_barrier();
    const u16* baseA = lds + b*4096;
    const u16* baseB = lds + 12288 + b*4096;
    s16x8 af[4], bfr[4];
    #pragma unroll
    for(int m=0;m<4;m++) af[m]  = *(const s16x8*)(baseA + ((wr<<6)+(m<<4)+lr)*32 + lk);
    #pragma unroll
    for(int n=0;n<4;n++) bfr[n] = *(const s16x8*)(baseB + ((wc<<6)+(n<<4)+lr)*32 + lk);
    asm volatile("s_waitcnt lgkmcnt(0)" ::: "memory");
    __builtin_amdgcn_sched_barrier(0);
    __builtin_amdgcn_s_barrier();
    if (it+3 < NIT) STG4(b, kbeg + ((it+3)<<5));
    #pragma unroll
    for(int m=0;m<4;m++)
      #pragma unroll
      for(int n=0;n<4;n++)
        acc[m][n] = __builtin_amdgcn_mfma_f32_16x16x32_bf16(af[m], bfr[n], acc[m][n], 0,0,0);
  }
  {
    const int it = NIT-2; const int b = it - (it/3)*3;
    waitv<4>();
    __builtin_amdgcn_s_barrier();
    const u16* baseA = lds + b*4096;
    const u16* baseB = lds + 12288 + b*4096;
    s16x8 af[4], bfr[4];
    #pragma unroll
    for(int m=0;m<4;m++) af[m]  = *(const s16x8*)(baseA + ((wr<<6)+(m<<4)+lr)*32 + lk);
    #pragma unroll
    for(int n=0;n<4;n++) bfr[n] = *(const s16x8*)(baseB + ((wc<<6)+(n<<4)+lr)*32 + lk);
    #pragma unroll
    for(int m=0;m<4;m++)
      #pragma unroll
      for(int n=0;n<4;n++)
        acc[m][n] = __builtin_amdgcn_mfma_f32_16x16x32_bf16(af[m], bfr[n], acc[m][n], 0,0,0);
  }
  {
    const int it = NIT-1; const int b = it - (it/3)*3;
    waitv<0>();
    __builtin_amdgcn_s_barrier();
    const u16* baseA = lds + b*4096;
    const u16* baseB = lds + 12288 + b*4096;
    s16x8 af[4], bfr[4];
    #pragma unroll
    for(int m=0;m<4;m++) af[m]  = *(const s16x8*)(baseA + ((wr<<6)+(m<<4)+lr)*32 + lk);
    #pragma unroll
    for(int n=0;n<4;n++) bfr[n] = *(const s16x8*)(baseB + ((wc<<6)+(n<<4)+lr)*32 + lk);
    #pragma unroll
    for(int m=0;m<4;m++)
      #pragma unroll
      for(int n=0;n<4;n++)
        acc[m][n] = __builtin_amdgcn_mfma_f32_16x16x32_bf16(af[m], bfr[n], acc[m][n], 0,0,0);
  }

  // MODE 1: min/max from registers (before LDS reuse)
  float tmin = 3.0e38f, tmax = -3.0e38f;
  if (MODE==1){
    #pragma unroll
    for(int m=0;m<4;m++)
      #pragma unroll
      for(int n=0;n<4;n++){
        f32x4 v = acc[m][n];
        #pragma unroll
        for(int e=0;e<4;e++){ tmin = fminf(tmin,v[e]); tmax = fmaxf(tmax,v[e]); }
      }
  }

  __syncthreads();
  u16* lC = lds;
  {
    const int rb_l = (wr<<6) + ((lane>>4)<<2);
    const int cb_l = (wc<<6) + lr;
    #pragma unroll
    for(int m=0;m<4;m++)
      #pragma unroll
      for(int n=0;n<4;n++){
        f32x4 v = acc[m][n];
        #pragma unroll
        for(int e=0;e<4;e++)
          lC[(rb_l+(m<<4)+e)*128 + cb_l+(n<<4)] = f2b(v[e]);
      }
  }
  __syncthreads();
  u16* Cp = (MODE==0) ? (Cb + (size_t)blockIdx.z * M * Nc) : Cb;
  #pragma unroll
  for(int q=0;q<8;q++){
    int c = (q<<8) + tid;
    int r = c>>4, cc = (c&15)<<3;
    s16x8 v = *(const s16x8*)(lC + r*128 + cc);
    if (MODE==1)
      __builtin_nontemporal_store(v, (s16x8*)(Cp + (size_t)(m0+r)*Nc + n0 + cc));
    else
      *(s16x8*)(Cp + (size_t)(m0+r)*Nc + n0 + cc) = v;
  }

  if (MODE==1){
    tmin = wave_min(tmin); tmax = wave_max(tmax);
    __shared__ float rmn[4], rmx[4];
    if(lane==0){ rmn[wid]=tmin; rmx[wid]=tmax; }
    __syncthreads();
    if(tid==0){
      float mn=fminf(fminf(rmn[0],rmn[1]),fminf(rmn[2],rmn[3]));
      float mx=fmaxf(fmaxf(rmx[0],rmx[1]),fmaxf(rmx[2],rmx[3]));
      atomicMin(mmx+0, fkey(mn));
      atomicMax(mmx+1, fkey(mx));
    }
  }
}

// copy strictly-upper 128-blocks of C[N][N] to lower, transposed (32x32 tiles)
__global__ __launch_bounds__(256) void mirror_lower(u16* __restrict__ C)
{
  int c0 = blockIdx.x<<5, r0 = blockIdx.y<<5;   // source tile (upper)
  if ((r0>>7) >= (c0>>7)) return;               // only strictly-upper 128-blocks
  __shared__ u16 t[32][33];
  int tx = threadIdx.x&31, ty = threadIdx.x>>5;
  #pragma unroll
  for(int i=0;i<32;i+=8) t[ty+i][tx] = C[(size_t)(r0+ty+i)*N_ + c0+tx];
  __syncthreads();
  #pragma unroll
  for(int i=0;i<32;i+=8)
    __builtin_nontemporal_store(t[tx][ty+i], C + (size_t)(c0+ty+i)*N_ + r0+tx);
}

// src [R][C] fp32 -> dst [C][R] bf16   (weight prep)
__global__ __launch_bounds__(256) void transpose_cast(
  const float* __restrict__ src, u16* __restrict__ dst, int R, int C)
{
  __shared__ float t[32][33];
  int c0 = blockIdx.x<<5, r0 = blockIdx.y<<5;
  int tx = threadIdx.x&31, ty = threadIdx.x>>5;
  #pragma unroll
  for(int i=0;i<32;i+=8) t[ty+i][tx] = src[(size_t)(r0+ty+i)*C + c0+tx];
  __syncthreads();
  #pragma unroll
  for(int i=0;i<32;i+=8) dst[(size_t)(c0+ty+i)*R + r0+tx] = f2b(t[tx][ty+i]);
}

// dst[C][R] bf16 = transpose( sum_p bf16_plane_p [R][C] ); gated (dense path)
__global__ __launch_bounds__(256) void transpose_sum_bf(
  const u16* __restrict__ src, size_t pstr, int nsp,
  u16* __restrict__ dst, int R, int C, const unsigned* __restrict__ gate)
{
  if (gate && gate[2] <= SPARSE_MAX) return;
  __shared__ float t[32][33];
  int c0 = blockIdx.x<<5, r0 = blockIdx.y<<5;
  int tx = threadIdx.x&31, ty = threadIdx.x>>5;
  #pragma unroll
  for(int i=0;i<32;i+=8){
    float v = 0;
    for(int p=0;p<nsp;p++)
      v += b2f(src[(size_t)p*pstr + (size_t)(r0+ty+i)*C + c0+tx]);
    t[ty+i][tx] = v;
  }
  __syncthreads();
  #pragma unroll
  for(int i=0;i<32;i+=8) dst[(size_t)(c0+ty+i)*R + r0+tx] = f2b(t[tx][ty+i]);
}

__global__ __launch_bounds__(256) void prep_x(const float* __restrict__ x,
  u16* __restrict__ xb, u16* __restrict__ xnb)
{
  int row = blockIdx.x, t = threadIdx.x;
  const float* p = x + (size_t)row*L_ + (t<<2);
  f32x4 v = *(const f32x4*)p;
  float ss = v[0]*v[0]+v[1]*v[1]+v[2]*v[2]+v[3]*v[3];
  float tot = blk_sum256(ss);
  float inv = 1.0f/fmaxf(sqrtf(tot), 1e-12f);
  u16* pb = xb  + (size_t)row*L_ + (t<<2);
  u16* pn = xnb + (size_t)row*L_ + (t<<2);
  #pragma unroll
  for(int k=0;k<4;k++){ pb[k]=f2b(v[k]); pn[k]=f2b(v[k]*inv); }
}

// fused-projection epilogue: a at cols [0,256), b at [256,512) of [N,1536] planes
__global__ __launch_bounds__(256) void attn_epi(const u16* __restrict__ SPA,
  size_t pstr, int nsp,
  const float* __restrict__ ba, const float* __restrict__ bb,
  const float* __restrict__ wc, const float* __restrict__ bc,
  float* __restrict__ agg, float* __restrict__ s)
{
  int row = (blockIdx.x<<2) + (threadIdx.x>>6);
  int lane = threadIdx.x&63;
  float a[4]={0,0,0,0}, b[4]={0,0,0,0};
  for(int p=0;p<nsp;p++){
    s16x4 ua = *(const s16x4*)(SPA + (size_t)p*pstr + (size_t)row*1536 + (lane<<2));
    s16x4 ub = *(const s16x4*)(SPA + (size_t)p*pstr + (size_t)row*1536 + 256 + (lane<<2));
    #pragma unroll
    for(int j=0;j<4;j++){ a[j]+=b2f((u16)ua[j]); b[j]+=b2f((u16)ub[j]); }
  }
  float acc=0;
  #pragma unroll
  for(int j=0;j<4;j++){
    int h = (lane<<2)+j;
    float tv = tanhf(a[j]+ba[h]);
    float sg = 1.0f/(1.0f+expf(-(b[j]+bb[h])));
    acc += tv*sg*wc[h];
  }
  acc = wave_sum(acc);
  if(lane==0){
    float v = acc + bc[0];
    agg[row]=v;
    s[row]=1.0f/(1.0f+expf(-v));
  }
}

__global__ __launch_bounds__(256) void s_stats(const float* __restrict__ s, float* __restrict__ sc){
  int t=threadIdx.x;
  float sum=0, mn=3e38f, mx=-3e38f;
  for(int i=t;i<N_;i+=256){ float v=s[i]; sum+=v; mn=fminf(mn,v); mx=fmaxf(mx,v); }
  float S=blk_sum256(sum);
  float MN=blk_min256(mn);
  float MX=blk_max256(mx);
  if(t==0){ sc[0]=S; sc[1]=MN; sc[2]=MX; }
}

__global__ __launch_bounds__(256) void aw_write(const float* __restrict__ maps, const float* __restrict__ s,
  const float* __restrict__ sc, u16* __restrict__ awb)
{
  int i = blockIdx.x, t = threadIdx.x;
  float smin = sc[1], smax = sc[2];
  float mn = smin*smin, mx = smax*smax;
  float beta = 0.6f/(mx-mn);
  float c1 = 0.4f - beta*mn;
  float si = s[i];
  const float* mrow = maps + (size_t)i*N_;
  float mv[24];
  float part = 0;
  #pragma unroll
  for(int q=0;q<24;q++){
    int j = t + (q<<8);
    mv[q] = c1 + beta*si*s[j] + mrow[j];
    part += mv[q];
  }
  float r = blk_sum256(part);
  float inv = 1.0f/fmaxf(r, 1e-12f);
  u16* orow = awb + (size_t)i*N_;
  #pragma unroll
  for(int q=0;q<24;q++)
    __builtin_nontemporal_store(f2b(mv[q]*inv), orow + t + (q<<8));
}

// out = relu(LN( (sum_p Y_p)*rowscale + bias )).  Gated sparse: read Yalt.
__global__ __launch_bounds__(256) void ln_epi512(const u16* __restrict__ Y, size_t pstr, int nsp,
  int rs, int cbase,
  const float* __restrict__ ki,
  const float* __restrict__ bias, const float* __restrict__ g, const float* __restrict__ bn,
  u16* __restrict__ outb,
  const unsigned* __restrict__ gate, const u16* __restrict__ Yalt)
{
  const u16* src = Y; size_t ps = pstr; int np = nsp, rstride = rs, cb = cbase;
  if (gate && gate[2] <= SPARSE_MAX){ src = Yalt; ps = 0; np = 1; rstride = 512; cb = 0; }
  int row = (blockIdx.x<<2)+(threadIdx.x>>6);
  int lane = threadIdx.x&63;
  int c0 = lane<<3;
  float v[8] = {0,0,0,0,0,0,0,0};
  for(int p=0;p<np;p++){
    s16x8 u = *(const s16x8*)(src + (size_t)p*ps + (size_t)row*rstride + cb + c0);
    #pragma unroll
    for(int j=0;j<8;j++) v[j] += b2f((u16)u[j]);
  }
  float scale = ki ? (1.0f/ki[row]) : 1.0f;
  float sum=0, ssum=0;
  #pragma unroll
  for(int j=0;j<8;j++){ v[j] = v[j]*scale + bias[c0+j]; sum+=v[j]; ssum+=v[j]*v[j]; }
  sum = wave_sum(sum); ssum = wave_sum(ssum);
  float m = sum*(1.0f/D_);
  float var = ssum*(1.0f/D_) - m*m;
  float invsd = rsqrtf(var + 1e-5f);
  u16 ob[8];
  #pragma unroll
  for(int j=0;j<8;j++){
    float o = (v[j]-m)*invsd*g[c0+j] + bn[c0+j];
    o = fmaxf(o, 0.0f);
    ob[j] = f2b(o);
  }
  *(s16x8*)(outb + (size_t)row*D_ + c0) = *(s16x8*)ob;
}

__global__ __launch_bounds__(256) void bias_cast(const u16* __restrict__ Y, size_t pstr, int nsp,
  const float* __restrict__ b, u16* __restrict__ outb)
{
  size_t idx = ((size_t)blockIdx.x*256 + threadIdx.x)<<3;
  float v[8] = {0,0,0,0,0,0,0,0};
  for(int p=0;p<nsp;p++){
    s16x8 u = *(const s16x8*)(Y + (size_t)p*pstr + idx);
    #pragma unroll
    for(int j=0;j<8;j++) v[j] += b2f((u16)u[j]);
  }
  int c = (int)(idx & (D_-1));
  u16 ob[8];
  #pragma unroll
  for(int k=0;k<8;k++) ob[k] = f2b(v[k]+b[c+k]);
  *(s16x8*)(outb+idx) = *(s16x8*)ob;
}

__global__ void init_k(unsigned* mmx){ mmx[0]=0xFFFFFFFFu; mmx[1]=0u; mmx[2]=0u; }

// read-only binarize: bitmap + per-row count + max-nnz + fused trans/z.
// Does NOT rewrite BIG (sparse path never reads it).
__global__ __launch_bounds__(256) void binarize(const u16* __restrict__ csb,
  unsigned* __restrict__ mmx, const float* __restrict__ agg,
  float* __restrict__ ki, float* __restrict__ z, u64* __restrict__ bm)
{
  int i = blockIdx.x, t = threadIdx.x;
  int lane = t&63, w = t>>6;
  float mn = funkey(mmx[0]), mx = funkey(mmx[1]);
  float th = mn + 0.5f*(mx-mn);
  const u16* row = csb + (size_t)i*N_;
  u64* bmrow = bm + (size_t)i*96;
  float cnt = 0, dot = 0;
  #pragma unroll
  for(int q=0;q<24;q++){
    int j = t + (q<<8);
    bool on = b2f(row[j]) >= th;
    u64 mask = __ballot(on);
    if(lane==0) bmrow[(q<<2)+w] = mask;
    if(on){ cnt += 1.0f; dot += agg[j]; }
  }
  float k = blk_sum256(cnt);
  float dt = blk_sum256(dot);
  if(t==0){
    ki[i] = k;
    float tr = dt/(k*sqrtf((float)N_));
    z[i] = 0.3f*tr + 0.7f*agg[i];
    atomicMax(mmx+2, (unsigned)(k+0.5f));
  }
}

// dense-fallback only: rewrite BIG in place as 0/1 bf16
__global__ __launch_bounds__(256) void binarize_store(u16* __restrict__ csb,
  const unsigned* __restrict__ mmx)
{
  if (mmx[2] <= SPARSE_MAX) return;
  int i = blockIdx.x, t = threadIdx.x;
  float mn = funkey(mmx[0]), mx = funkey(mmx[1]);
  float th = mn + 0.5f*(mx-mn);
  u16* row = csb + (size_t)i*N_;
  #pragma unroll
  for(int q=0;q<24;q++){
    int j = t + (q<<8);
    row[j] = (b2f(row[j]) >= th) ? (u16)0x3F80 : (u16)0;
  }
}

// sparse adjacency apply: YS[i,:] = sum_{j: bit set} sum_p SP[p][j,:]
__global__ __launch_bounds__(256) void gather_rows(const u64* __restrict__ bm,
  const u16* __restrict__ SPp, size_t pstr, int nsp,
  const unsigned* __restrict__ gate, u16* __restrict__ YS)
{
  if (gate[2] > SPARSE_MAX) return;
  int i = blockIdx.x, t = threadIdx.x;
  __shared__ u64 wbuf[96];
  __shared__ u16 idx[SPARSE_MAX];
  __shared__ int nn_s;
  if (t < 96) wbuf[t] = bm[(size_t)i*96 + t];
  __syncthreads();
  if (t == 0){
    int nn = 0;
    for(int k=0;k<96;k++){
      u64 m = wbuf[k];
      while(m && nn < (int)SPARSE_MAX){
        int b = __ffsll((long long)m) - 1;
        m &= m - 1;
        idx[nn++] = (u16)((k<<6) + b);
      }
    }
    nn_s = nn;
  }
  __syncthreads();
  int nn = nn_s;
  float a0=0, a1=0;
  for(int k=0;k<nn;k++){
    size_t jb = (size_t)idx[k]*512;
    for(int p=0;p<nsp;p++){
      a0 += b2f(SPp[p*pstr + jb + t]);
      a1 += b2f(SPp[p*pstr + jb + t + 256]);
    }
  }
  YS[(size_t)i*512 + t]       = f2b(a0);
  YS[(size_t)i*512 + t + 256] = f2b(a1);
}

__global__ __launch_bounds__(1024) void softmax_prep(const float* __restrict__ z,
  float* __restrict__ e, float* __restrict__ sexp)
{
  int t = threadIdx.x;
  __shared__ float sm[16];
  float mx=-3e38f;
  for(int i=t;i<N_;i+=1024) mx=fmaxf(mx,z[i]);
  mx = wave_max(mx);
  if((t&63)==0) sm[t>>6]=mx;
  __syncthreads();
  float zm = sm[0];
  #pragma unroll
  for(int w=1;w<16;w++) zm=fmaxf(zm,sm[w]);
  __syncthreads();
  float sum=0;
  for(int i=t;i<N_;i+=1024){ float ee=expf(z[i]-zm); e[i]=ee; sum+=ee; }
  sum = wave_sum(sum);
  if((t&63)==0) sm[t>>6]=sum;
  __syncthreads();
  if(t==0){ float S=0; for(int w=0;w<16;w++) S+=sm[w]; *sexp=S; }
}

// pooled partial sums over 192 rows/block; g2/g1 are bf16 [N,512]
__global__ __launch_bounds__(256) void pooled_partial(const float* __restrict__ e,
  const u16* __restrict__ g2b, const u16* __restrict__ g1b, float* __restrict__ part)
{
  int b = blockIdx.x, t = threadIdx.x;
  float a0=0,a1=0,a2=0,a3=0;
  for(int r=0;r<192;r++){
    int row = b*192+r;
    float w = e[row];
    a0 += w * b2f(g2b[(size_t)row*D_ + t]);
    a1 += w * b2f(g2b[(size_t)row*D_ + t+256]);
    a2 += w * b2f(g1b[(size_t)row*D_ + t]);
    a3 += w * b2f(g1b[(size_t)row*D_ + t+256]);
  }
  part[(size_t)b*1024 + t]      = a0;
  part[(size_t)b*1024 + t+256]  = a1;
  part[(size_t)b*1024 + t+512]  = a2;
  part[(size_t)b*1024 + t+768]  = a3;
}

__global__ __launch_bounds__(1024) void final_k(const float* __restrict__ part, const float* __restrict__ sexp,
  const float* __restrict__ lng, const float* __restrict__ lnb,
  const float* __restrict__ clsw, float* __restrict__ out)
{
  int t = threadIdx.x;
  __shared__ float red[16];
  __shared__ float smv[1024];
  __shared__ float lgs[4];
  float p=0;
  for(int b=0;b<32;b++) p += part[b*1024 + t];
  p /= sexp[0];
  float w = wave_sum(p);
  if((t&63)==0) red[t>>6]=w;
  __syncthreads();
  float tot=0;
  #pragma unroll
  for(int i2=0;i2<16;i2++) tot+=red[i2];
  float m = tot*(1.0f/1024.0f);
  __syncthreads();
  float d = p-m;
  w = wave_sum(d*d);
  if((t&63)==0) red[t>>6]=w;
  __syncthreads();
  tot=0;
  #pragma unroll
  for(int i2=0;i2<16;i2++) tot+=red[i2];
  float var = tot*(1.0f/1024.0f);
  float y = d*rsqrtf(var+1e-5f)*lng[t] + lnb[t];
  smv[t]=y;
  __syncthreads();
  if(t<4){
    float lg=0;
    for(int j=0;j<1024;j++) lg += smv[j]*clsw[j*4+t];
    lgs[t]=lg;
  }
  __syncthreads();
  if(t==0){
    float h[4];
    int am=0; float best=lgs[0];
    #pragma unroll
    for(int c2=0;c2<4;c2++){ h[c2]=1.0f/(1.0f+expf(-lgs[c2])); if(lgs[c2]>best){best=lgs[c2];am=c2;} }
    float sv=1.0f;
    #pragma unroll
    for(int c2=0;c2<4;c2++){ out[c2]=h[c2]; sv*=(1.0f-h[c2]); out[4+c2]=sv; }
    out[8]=(float)am;
  }
}

extern "C" void kernel_launch(void* const* d_in, const int* in_sizes, int n_in,
                              void* d_out, int out_size, void* d_ws, size_t ws_size,
                              hipStream_t stream)
{
  const float* x_path =(const float*)d_in[0];
  const float* maps   =(const float*)d_in[1];
  const float* nl0_w1 =(const float*)d_in[2];
  const float* nl0_b1 =(const float*)d_in[3];
  const float* nl0_g  =(const float*)d_in[4];
  const float* nl0_bn =(const float*)d_in[5];
  const float* nl0_w2 =(const float*)d_in[6];
  const float* nl0_b2 =(const float*)d_in[7];
  const float* nl1_w1 =(const float*)d_in[8];
  const float* nl1_b1 =(const float*)d_in[9];
  const float* nl1_g  =(const float*)d_in[10];
  const float* nl1_bn =(const float*)d_in[11];
  const float* nl1_w2 =(const float*)d_in[12];
  const float* nl1_b2 =(const float*)d_in[13];
  const float *gw[6], *gb[6], *gg[6], *gbn[6];   // gc0,gc1,gc2,ga0,ga1,ga2
  for(int l=0;l<6;l++){
    gw[l]  = (const float*)d_in[14+l*4+0];
    gb[l]  = (const float*)d_in[14+l*4+1];
    gg[l]  = (const float*)d_in[14+l*4+2];
    gbn[l] = (const float*)d_in[14+l*4+3];
  }
  const float* attn_wa=(const float*)d_in[38];
  const float* attn_ba=(const float*)d_in[39];
  const float* attn_wb=(const float*)d_in[40];
  const float* attn_bb=(const float*)d_in[41];
  const float* attn_wc=(const float*)d_in[42];
  const float* attn_bc=(const float*)d_in[43];
  const float* cls_w  =(const float*)d_in[44];
  const float* ln_g   =(const float*)d_in[45];
  const float* ln_b   =(const float*)d_in[46];

  char* ws=(char*)d_ws;
  size_t off=0;
  auto alc=[&](size_t b)->char*{ char* p=ws+off; off=(off+b+255)&~(size_t)255; return p; };
  u16* BIG = (u16*)alc((size_t)N_*N_*2);          // aw, then cs gram (time-shared)
  u16* XB  = (u16*)alc((size_t)N_*L_*2);
  u16* XNB = (u16*)alc((size_t)N_*L_*2);
  u16* WT_proj=(u16*)alc((size_t)1536*L_*2);      // [wa;wb;nl0w1;nl1w1] transposed
  u16* WT_nl0w2=(u16*)alc((size_t)D_*D_*2);
  u16* WT_nl1w2=(u16*)alc((size_t)D_*D_*2);
  u16* WT_g[6];
  for(int l=0;l<6;l++) WT_g[l]=(u16*)alc((size_t)D_*D_*2);
  u16* SP = (u16*)alc((size_t)2*N_*1536*2);       // planes: proj SK2 or 6x[N,512]
  u16* XWT=(u16*)alc((size_t)D_*N_*2);
  u16* XA0=(u16*)alc((size_t)N_*D_*2);
  u16* XA1=(u16*)alc((size_t)N_*D_*2);
  u16* X0B=(u16*)alc((size_t)N_*D_*2);
  u16* X1B=(u16*)alc((size_t)N_*D_*2);
  u16* YS =(u16*)alc((size_t)N_*D_*2);
  u64* BM =(u64*)alc((size_t)N_*96*8);
  float* PART=(float*)alc((size_t)32*1024*4);
  float* AGG=(float*)alc(N_*4);
  float* SS =(float*)alc(N_*4);
  float* KI =(float*)alc(N_*4);
  float* Z  =(float*)alc(N_*4);
  float* E  =(float*)alc(N_*4);
  float* SC =(float*)alc(256);
  unsigned* MMX=(unsigned*)alc(256);
  float* SEXP=(float*)alc(256);

  const size_t PS_D = (size_t)N_*D_;      // 512-col plane stride
  const size_t PS_P = (size_t)N_*1536;    // proj plane stride

  init_k<<<1,1,0,stream>>>(MMX);
  prep_x<<<N_,256,0,stream>>>(x_path, XB, XNB);

  // weight prep
  transpose_cast<<<dim3(H_/32, L_/32),256,0,stream>>>(attn_wa, WT_proj,                   L_, H_);
  transpose_cast<<<dim3(H_/32, L_/32),256,0,stream>>>(attn_wb, WT_proj + (size_t)256*L_,  L_, H_);
  transpose_cast<<<dim3(D_/32, L_/32),256,0,stream>>>(nl0_w1,  WT_proj + (size_t)512*L_,  L_, D_);
  transpose_cast<<<dim3(D_/32, L_/32),256,0,stream>>>(nl1_w1,  WT_proj + (size_t)1024*L_, L_, D_);
  transpose_cast<<<dim3(D_/32, D_/32),256,0,stream>>>(nl0_w2, WT_nl0w2, D_, D_);
  transpose_cast<<<dim3(D_/32, D_/32),256,0,stream>>>(nl1_w2, WT_nl1w2, D_, D_);
  for(int l=0;l<6;l++)
    transpose_cast<<<dim3(D_/32, D_/32),256,0,stream>>>(gw[l], WT_g[l], D_, D_);

  // fused X projections: [a|b|h0|h1] = XB @ WT_proj^T  (SK=2)
  gemm_bt<0><<<dim3(1536/128, N_/128, 2),256,0,stream>>>(XB, WT_proj, N_, 1536, L_, SP, nullptr, nullptr);
  attn_epi<<<N_/4,256,0,stream>>>(SP, PS_P, 2, attn_ba, attn_bb, attn_wc, attn_bc, AGG, SS);
  s_stats<<<1,256,0,stream>>>(SS,SC);
  aw_write<<<N_,256,0,stream>>>(maps,SS,SC,BIG);

  ln_epi512<<<N_/4,256,0,stream>>>(SP,PS_P,2, 1536,1024, nullptr, nl1_b1,nl1_g,nl1_bn, XA1, nullptr,nullptr);
  ln_epi512<<<N_/4,256,0,stream>>>(SP,PS_P,2, 1536, 512, nullptr, nl0_b1,nl0_g,nl0_bn, XA0, nullptr,nullptr);

  gemm_bt<0><<<dim3(D_/128,N_/128,4),256,0,stream>>>(XA1, WT_nl1w2, N_,D_,D_, SP, nullptr, nullptr);
  bias_cast<<<(N_*D_/8)/256,256,0,stream>>>(SP,PS_D,4, nl1_b2, X1B);

  // ga chain (dense adjacency = BIG = aw); adjacency GEMM split-K=6
  {
    const u16* cur=X1B;
    for(int l=0;l<3;l++){
      int gi = 3+l;
      gemm_bt<0><<<dim3(D_/128,N_/128,4),256,0,stream>>>(cur, WT_g[gi], N_,D_,D_, SP, nullptr, nullptr);
      transpose_sum_bf<<<dim3(D_/32, N_/32),256,0,stream>>>(SP, PS_D, 4, XWT, N_, D_, nullptr);
      gemm_bt<0><<<dim3(D_/128,N_/128,6),256,0,stream>>>(BIG, XWT, N_,D_,N_, SP, nullptr, nullptr);
      u16* nxt = (l==0)? XA1 : (l==1)? YS : X1B;
      ln_epi512<<<N_/4,256,0,stream>>>(SP,PS_D,6, 512,0, nullptr, gb[gi],gg[gi],gbn[gi], nxt, nullptr,nullptr);
      cur = nxt;
    }
  }

  gemm_bt<0><<<dim3(D_/128,N_/128,4),256,0,stream>>>(XA0, WT_nl0w2, N_,D_,D_, SP, nullptr, nullptr);
  bias_cast<<<(N_*D_/8)/256,256,0,stream>>>(SP,PS_D,4, nl0_b2, X0B);

  // cosine gram (128-tile upper triangle) -> BIG + min/max; mirror; binarize
  gemm_bt<1><<<dim3(N_/128, N_/128, 1),256,0,stream>>>(XNB, XNB, N_,N_,L_, BIG, MMX, nullptr);
  mirror_lower<<<dim3(N_/32, N_/32),256,0,stream>>>(BIG);
  binarize<<<N_,256,0,stream>>>(BIG, MMX, AGG, KI, Z, BM);
  binarize_store<<<N_,256,0,stream>>>(BIG, MMX);     // dense fallback only

  // gc chain: sparse gather path (gated) with dense GEMM fallback
  {
    const u16* cur=X0B;
    for(int l=0;l<3;l++){
      int gi = l;
      gemm_bt<0><<<dim3(D_/128,N_/128,4),256,0,stream>>>(cur, WT_g[gi], N_,D_,D_, SP, nullptr, nullptr);
      transpose_sum_bf<<<dim3(D_/32, N_/32),256,0,stream>>>(SP, PS_D, 4, XWT, N_, D_, MMX);
      gemm_bt<0><<<dim3(D_/128,N_/128,6),256,0,stream>>>(BIG, XWT, N_,D_,N_, SP, nullptr, MMX);
      gather_rows<<<N_,256,0,stream>>>(BM, SP, PS_D, 4, MMX, YS);
      u16* nxt = (l==0)? XA1 : (l==1)? XA0 : X0B;
      ln_epi512<<<N_/4,256,0,stream>>>(SP,PS_D,6, 512,0, KI, gb[gi],gg[gi],gbn[gi], nxt, MMX, YS);
      cur = nxt;
    }
  }

  // pooling + head
  softmax_prep<<<1,1024,0,stream>>>(Z,E,SEXP);
  pooled_partial<<<32,256,0,stream>>>(E,X1B,X0B,PART);
  final_k<<<1,1024,0,stream>>>(PART,SEXP,ln_g,ln_b,cls_w,(float*)d_out);

  (void)in_sizes;(void)n_in;(void)out_size;(void)ws_size;
}